// Round 4
// baseline (4302.290 us; speedup 1.0000x reference)
//
#include <hip/hip_runtime.h>
#include <math.h>

#define B_ 32
#define S_ 64
#define H_ 300
#define M_ 2048          // B*S
#define EPSF 1e-8f

typedef _Float16 f16;
typedef _Float16 f16x4 __attribute__((ext_vector_type(4)));
typedef _Float16 f16x8 __attribute__((ext_vector_type(8)));
typedef float f32x4 __attribute__((ext_vector_type(4)));

// ---------------- transpose (R x C) -> (C x R) ----------------
__global__ __launch_bounds__(256) void k_transpose(const float* __restrict__ src,
        float* __restrict__ dst, int R, int C) {
  __shared__ float t[32][33];
  int tx = threadIdx.x & 31, ty = threadIdx.x >> 5;
  int c0 = blockIdx.x * 32, r0 = blockIdx.y * 32;
  #pragma unroll
  for (int q = 0; q < 4; ++q) {
    int r = r0 + ty + q * 8, c = c0 + tx;
    t[ty + q * 8][tx] = (r < R && c < C) ? src[(size_t)r * C + c] : 0.f;
  }
  __syncthreads();
  #pragma unroll
  for (int q = 0; q < 4; ++q) {
    int c = c0 + ty + q * 8, r = r0 + tx;
    if (c < C && r < R) dst[(size_t)c * R + r] = t[tx][ty + q * 8];
  }
}

// ---- Whh (1200x300 f32) -> f16 padded [4 g][320 u][320 k], zeros outside ----
__global__ __launch_bounds__(256) void k_wh16(const float* __restrict__ W,
        f16* __restrict__ D) {
  int idx = blockIdx.x * 256 + threadIdx.x;
  if (idx >= 409600) return;
  int g = idx / 102400, rem = idx - g * 102400;
  int u = rem / 320, k = rem - u * 320;
  float v = (u < 300 && k < 300) ? W[((size_t)g * 300 + u) * 300 + k] : 0.f;
  D[idx] = (f16)v;
}

// ---------------- input-projection GEMM, scatter to f16 fragment layout ----
// z[m,n]=sum_k A[row(m),k]*WT[k,n]+bias[n] -> XG2 f16 layout:
// [(rec*64+t)*10+jw]*4096 + ((g*2+nh)*16+lo)*32 + half*16 + hi*4 + r
__global__ __launch_bounds__(256) void k_proj(const float* __restrict__ A,
        const int* __restrict__ gather, const float* __restrict__ WT,
        const float* __restrict__ bias, f16* __restrict__ XG2,
        int N, int K, int lda, int rec, int rev) {
  __shared__ float As[16][66];
  __shared__ float Bs[16][66];
  int tid = threadIdx.x;
  int m0 = blockIdx.x * 64, n0 = blockIdx.y * 64;
  int tx = tid & 15, ty = tid >> 4;
  int ar = tid >> 2, ac = (tid & 3) * 4;
  int br = tid >> 4, bc = (tid & 15) * 4;
  int gm = m0 + ar;
  const float* Arow = gather ? (A + (size_t)gather[gm] * lda)
                             : (A + (size_t)gm * lda);
  float acc[4][4] = {};
  int nk = (K + 15) / 16;
  for (int kc = 0; kc < nk; ++kc) {
    int k0 = kc * 16;
    if (k0 + 16 <= K) {
      float4 av = *(const float4*)(Arow + k0 + ac);
      As[ac + 0][ar] = av.x; As[ac + 1][ar] = av.y;
      As[ac + 2][ar] = av.z; As[ac + 3][ar] = av.w;
    } else {
      #pragma unroll
      for (int q = 0; q < 4; ++q) {
        int k = k0 + ac + q;
        As[ac + q][ar] = (k < K) ? Arow[k] : 0.f;
      }
    }
    {
      int kk = k0 + br, n = n0 + bc;
      if (kk < K && n + 3 < N) {
        float4 bv = *(const float4*)(WT + (size_t)kk * N + n);
        Bs[br][bc + 0] = bv.x; Bs[br][bc + 1] = bv.y;
        Bs[br][bc + 2] = bv.z; Bs[br][bc + 3] = bv.w;
      } else {
        #pragma unroll
        for (int q = 0; q < 4; ++q) {
          int n2 = n + q;
          Bs[br][bc + q] = (kk < K && n2 < N) ? WT[(size_t)kk * N + n2] : 0.f;
        }
      }
    }
    __syncthreads();
    #pragma unroll
    for (int kk = 0; kk < 16; ++kk) {
      float av[4], bv[4];
      #pragma unroll
      for (int i = 0; i < 4; ++i) av[i] = As[kk][ty * 4 + i];
      #pragma unroll
      for (int j = 0; j < 4; ++j) bv[j] = Bs[kk][tx * 4 + j];
      #pragma unroll
      for (int i = 0; i < 4; ++i)
        #pragma unroll
        for (int j = 0; j < 4; ++j) acc[i][j] += av[i] * bv[j];
    }
    __syncthreads();
  }
  #pragma unroll
  for (int i = 0; i < 4; ++i) {
    int m = m0 + ty * 4 + i;
    int b = m >> 6, s = m & 63;
    int t = rev ? 63 - s : s;
    int half = b >> 4, bl = b & 15;
    int hi2 = bl >> 2, r2 = bl & 3;
    #pragma unroll
    for (int j = 0; j < 4; ++j) {
      int n = n0 + tx * 4 + j;
      if (n < N) {
        float v = acc[i][j] + bias[n];
        int g = n / 300, u = n - g * 300;
        int jw = u >> 5, ul = u & 31;
        int nh = ul >> 4, lo2 = ul & 15;
        size_t off = (((((size_t)(rec * 64 + t) * 10 + jw) * 4 + g) * 2 + nh) * 16 + lo2) * 32
                     + half * 16 + hi2 * 4 + r2;
        XG2[off] = (f16)v;
      }
    }
  }
}

// ---------------- block-local MFMA LSTM, weights streamed from L2 ----------
// 8 blocks: rec = bid&3, half = bid>>2 (batch 16*half..+15). 10 waves;
// wave jw owns u-tile [jw*32, jw*32+32) for ALL 4 gates. Weight fragments
// are STREAMED each step (L2-resident, 800 KB/step/block); h via LDS only.
__global__ __launch_bounds__(640, 1) void k_lstm2(
    const f16* __restrict__ Wh, const f16* __restrict__ XG2,
    f16* __restrict__ Hfin, float* __restrict__ O) {
  int rec = blockIdx.x & 3, half = blockIdx.x >> 2;
  int tid = threadIdx.x;
  int jw = tid >> 6;
  int l = tid & 63, lo = l & 15, hi = l >> 4;
  int u0 = jw * 32;

  __shared__ f16 Hs[16][336];

  const f16* Wd = Wh + (size_t)(rec & 1) * 409600;
  // per-lane streaming base; offset(g,nh,kt) = g*102400 + nh*5120 + kt*32
  const f16* wb = Wd + (size_t)(u0 + lo) * 320 + hi * 8;

  for (int i = tid; i < 16 * 336; i += 640) ((f16*)Hs)[i] = (f16)0.f;
  float cst[2][4] = {};
  bool upad[2];
  upad[0] = (u0 + lo) >= 300;
  upad[1] = (u0 + 16 + lo) >= 300;
  __syncthreads();

  for (int t = 0; t < 64; ++t) {
    // xg fragment loads (consumed after MFMA -> latency hidden)
    const f16* xt = XG2 + ((size_t)(rec * 64 + t) * 10 + jw) * 4096 + half * 16 + hi * 4;
    f16x4 xv[4][2];
    #pragma unroll
    for (int g = 0; g < 4; ++g)
      #pragma unroll
      for (int nh = 0; nh < 2; ++nh)
        xv[g][nh] = *(const f16x4*)(xt + ((g * 2 + nh) * 16 + lo) * 32);

    f32x4 acc[4][2] = {};
    #pragma unroll 2
    for (int kt = 0; kt < 10; ++kt) {
      f16x8 Af = *(const f16x8*)(&Hs[lo][kt * 32 + hi * 8]);
      #pragma unroll
      for (int g = 0; g < 4; ++g)
        #pragma unroll
        for (int nh = 0; nh < 2; ++nh) {
          f16x8 bw = *(const f16x8*)(wb + (size_t)g * 102400 + nh * 5120 + kt * 32);
          acc[g][nh] = __builtin_amdgcn_mfma_f32_16x16x32_f16(
              Af, bw, acc[g][nh], 0, 0, 0);
        }
    }
    #pragma unroll
    for (int g = 0; g < 4; ++g)
      #pragma unroll
      for (int nh = 0; nh < 2; ++nh)
        if (!upad[nh])
          #pragma unroll
          for (int r = 0; r < 4; ++r)
            acc[g][nh][r] += (float)xv[g][nh][r];

    __syncthreads();   // all Hs reads done before overwrite

    int tt = (rec & 1) ? 63 - t : t;
    #pragma unroll
    for (int nh = 0; nh < 2; ++nh) {
      int u = u0 + nh * 16 + lo;
      #pragma unroll
      for (int r = 0; r < 4; ++r) {
        float zi = acc[0][nh][r], zf = acc[1][nh][r];
        float zg = acc[2][nh][r], zo = acc[3][nh][r];
        float c = cst[nh][r];
        float si = 1.f / (1.f + expf(-zi));
        float sf = 1.f / (1.f + expf(-zf));
        float so = 1.f / (1.f + expf(-zo));
        float cn = sf * c + si * tanhf(zg);
        float hn = so * tanhf(cn);
        cst[nh][r] = cn;
        Hs[hi * 4 + r][u] = (f16)hn;
        if (O && u < 300)
          O[((size_t)rec * 2048 + (half * 16 + hi * 4 + r) * 64 + tt) * 300 + u] = hn;
      }
    }
    __syncthreads();   // writes visible before next-step reads
  }

  // final h (valid after last barrier)
  for (int i = tid; i < 16 * 320; i += 640) {
    int b = i / 320, u = i - b * 320;
    Hfin[((size_t)rec * 32 + half * 16 + b) * 320 + u] = Hs[b][u];
  }
}

// ---------------- plain L2 norms of the 4 ctx outputs ----------------
__global__ __launch_bounds__(256) void k_norms(const float* __restrict__ O,
        float* __restrict__ NRM) {
  int idx = blockIdx.x * 4 + (threadIdx.x >> 6);
  int lane = threadIdx.x & 63;
  const float* p = O + (size_t)idx * 300;
  float s = 0.f;
  for (int h = lane; h < 300; h += 64) { float v = p[h]; s += v * v; }
  #pragma unroll
  for (int off = 32; off; off >>= 1) s += __shfl_xor(s, off);
  if (lane == 0) NRM[idx] = sqrtf(s);
}

// ---------------- cosine matrices ----------------
__global__ __launch_bounds__(256) void k_cos(const float* __restrict__ O,
        const float* __restrict__ NRM, float* __restrict__ COS) {
  int b = blockIdx.x, d = blockIdx.y;
  int r1 = d, r2 = 2 + d;
  const float* A = O + ((size_t)r1 * M_ + b * S_) * 300;
  const float* Bm = O + ((size_t)r2 * M_ + b * S_) * 300;
  __shared__ float As[64][33], Bs[64][33];
  int tid = threadIdx.x;
  int tx = tid & 15, ty = tid >> 4;
  int lr = tid >> 2, lc = (tid & 3) * 8;
  float acc[4][4] = {};
  for (int k0 = 0; k0 < 300; k0 += 32) {
    if (k0 + 32 <= 300) {
      float4 a0 = *(const float4*)(A + (size_t)lr * 300 + k0 + lc);
      float4 a1 = *(const float4*)(A + (size_t)lr * 300 + k0 + lc + 4);
      As[lr][lc + 0] = a0.x; As[lr][lc + 1] = a0.y; As[lr][lc + 2] = a0.z; As[lr][lc + 3] = a0.w;
      As[lr][lc + 4] = a1.x; As[lr][lc + 5] = a1.y; As[lr][lc + 6] = a1.z; As[lr][lc + 7] = a1.w;
      float4 b0 = *(const float4*)(Bm + (size_t)lr * 300 + k0 + lc);
      float4 b1 = *(const float4*)(Bm + (size_t)lr * 300 + k0 + lc + 4);
      Bs[lr][lc + 0] = b0.x; Bs[lr][lc + 1] = b0.y; Bs[lr][lc + 2] = b0.z; Bs[lr][lc + 3] = b0.w;
      Bs[lr][lc + 4] = b1.x; Bs[lr][lc + 5] = b1.y; Bs[lr][lc + 6] = b1.z; Bs[lr][lc + 7] = b1.w;
    } else {
      #pragma unroll
      for (int q = 0; q < 8; ++q) {
        int k = k0 + lc + q;
        As[lr][lc + q] = (k < 300) ? A[(size_t)lr * 300 + k] : 0.f;
        Bs[lr][lc + q] = (k < 300) ? Bm[(size_t)lr * 300 + k] : 0.f;
      }
    }
    __syncthreads();
    #pragma unroll
    for (int kk = 0; kk < 32; ++kk) {
      float av[4], bv[4];
      #pragma unroll
      for (int i = 0; i < 4; ++i) av[i] = As[ty * 4 + i][kk];
      #pragma unroll
      for (int j = 0; j < 4; ++j) bv[j] = Bs[tx * 4 + j][kk];
      #pragma unroll
      for (int i = 0; i < 4; ++i)
        #pragma unroll
        for (int j = 0; j < 4; ++j) acc[i][j] += av[i] * bv[j];
    }
    __syncthreads();
  }
  float n1[4], n2[4];
  #pragma unroll
  for (int i = 0; i < 4; ++i) {
    n1[i] = NRM[(size_t)r1 * M_ + b * S_ + ty * 4 + i];
    n2[i] = NRM[(size_t)r2 * M_ + b * S_ + tx * 4 + i];
  }
  float* outp = COS + ((size_t)d * 32 + b) * 4096;
  #pragma unroll
  for (int i = 0; i < 4; ++i)
    #pragma unroll
    for (int j = 0; j < 4; ++j)
      outp[(ty * 4 + i) * 64 + tx * 4 + j] = acc[i][j] / (n1[i] * n2[j]);
}

// ---------------- cos row/col sums ----------------
__global__ __launch_bounds__(64) void k_csum(const float* __restrict__ COS,
        float* __restrict__ RS, float* __restrict__ CS) {
  int b = blockIdx.x, d = blockIdx.y, t = threadIdx.x;
  const float* base = COS + ((size_t)d * 32 + b) * 4096;
  float rs = 0.f, cs = 0.f;
  for (int k = 0; k < 64; ++k) { rs += base[t * 64 + k]; cs += base[k * 64 + t]; }
  RS[(d * 32 + b) * 64 + t] = rs;
  CS[(d * 32 + b) * 64 + t] = cs;
}

// ---- pairwise match + fused max over i and j (PAIR never materialized) ----
__global__ __launch_bounds__(256) void k_pairfused(const float* __restrict__ O,
        const float* __restrict__ NRM, const float* __restrict__ Wf,
        const float* __restrict__ Wb, float* __restrict__ V1, float* __restrict__ V2) {
  int b = blockIdx.x, lidx = blockIdx.y, d = blockIdx.z;
  int r1 = d;
  const float* A = O + ((size_t)r1 * M_ + b * S_) * 300;
  const float* Bm = O + ((size_t)3 * M_ + b * S_) * 300;
  const float* Wl = (d ? Wb : Wf) + (size_t)lidx * 300;
  __shared__ float As[64][33], Bs[64][33];
  int tid = threadIdx.x;
  int tx = tid & 15, ty = tid >> 4;
  int lr = tid >> 2, lc = (tid & 3) * 8;
  float acc[4][4] = {};
  for (int k0 = 0; k0 < 300; k0 += 32) {
    if (k0 + 32 <= 300) {
      float4 a0 = *(const float4*)(A + (size_t)lr * 300 + k0 + lc);
      float4 a1 = *(const float4*)(A + (size_t)lr * 300 + k0 + lc + 4);
      float4 w0 = *(const float4*)(Wl + k0 + lc);
      float4 w1 = *(const float4*)(Wl + k0 + lc + 4);
      As[lr][lc + 0] = a0.x * w0.x * w0.x; As[lr][lc + 1] = a0.y * w0.y * w0.y;
      As[lr][lc + 2] = a0.z * w0.z * w0.z; As[lr][lc + 3] = a0.w * w0.w * w0.w;
      As[lr][lc + 4] = a1.x * w1.x * w1.x; As[lr][lc + 5] = a1.y * w1.y * w1.y;
      As[lr][lc + 6] = a1.z * w1.z * w1.z; As[lr][lc + 7] = a1.w * w1.w * w1.w;
      float4 b0 = *(const float4*)(Bm + (size_t)lr * 300 + k0 + lc);
      float4 b1 = *(const float4*)(Bm + (size_t)lr * 300 + k0 + lc + 4);
      Bs[lr][lc + 0] = b0.x; Bs[lr][lc + 1] = b0.y; Bs[lr][lc + 2] = b0.z; Bs[lr][lc + 3] = b0.w;
      Bs[lr][lc + 4] = b1.x; Bs[lr][lc + 5] = b1.y; Bs[lr][lc + 6] = b1.z; Bs[lr][lc + 7] = b1.w;
    } else {
      #pragma unroll
      for (int q = 0; q < 8; ++q) {
        int k = k0 + lc + q;
        float w = (k < 300) ? Wl[k] : 0.f;
        As[lr][lc + q] = (k < 300) ? A[(size_t)lr * 300 + k] * w * w : 0.f;
        Bs[lr][lc + q] = (k < 300) ? Bm[(size_t)lr * 300 + k] : 0.f;
      }
    }
    __syncthreads();
    #pragma unroll
    for (int kk = 0; kk < 32; ++kk) {
      float av[4], bv[4];
      #pragma unroll
      for (int i = 0; i < 4; ++i) av[i] = As[ty * 4 + i][kk];
      #pragma unroll
      for (int j = 0; j < 4; ++j) bv[j] = Bs[tx * 4 + j][kk];
      #pragma unroll
      for (int i = 0; i < 4; ++i)
        #pragma unroll
        for (int j = 0; j < 4; ++j) acc[i][j] += av[i] * bv[j];
    }
    __syncthreads();
  }
  float n1[4], n2[4];
  #pragma unroll
  for (int i = 0; i < 4; ++i) {
    n1[i] = NRM[(size_t)r1 * M_ + b * S_ + ty * 4 + i];
    n2[i] = NRM[(size_t)3 * M_ + b * S_ + tx * 4 + i];
  }
  int offv = (d ? 100 : 20) + lidx;
  float mj[4], mi[4];
  #pragma unroll
  for (int q = 0; q < 4; ++q) { mj[q] = -INFINITY; mi[q] = -INFINITY; }
  #pragma unroll
  for (int i = 0; i < 4; ++i)
    #pragma unroll
    for (int j = 0; j < 4; ++j) {
      float v = acc[i][j] / (n1[i] * n2[j]);
      mj[i] = fmaxf(mj[i], v);
      mi[j] = fmaxf(mi[j], v);
    }
  // max over j: reduce across tx (low 4 lane bits)
  #pragma unroll
  for (int off = 1; off < 16; off <<= 1)
    #pragma unroll
    for (int i = 0; i < 4; ++i) mj[i] = fmaxf(mj[i], __shfl_xor(mj[i], off));
  if (tx == 0)
    #pragma unroll
    for (int i = 0; i < 4; ++i)
      V1[((size_t)b * S_ + ty * 4 + i) * 160 + offv] = mj[i];
  // max over i: reduce across ty via LDS
  float* red = &As[0][0];        // reuse, 64*16 floats
  __syncthreads();
  #pragma unroll
  for (int j = 0; j < 4; ++j) red[(tx * 4 + j) * 16 + ty] = mi[j];
  __syncthreads();
  if (tid < 64) {
    float m = red[tid * 16];
    #pragma unroll
    for (int yy = 1; yy < 16; ++yy) m = fmaxf(m, red[tid * 16 + yy]);
    V2[((size_t)b * S_ + tid) * 160 + offv] = m;
  }
}

// ---------------- mean/max attention vectors MM[v][b][r][h] ----------------
__global__ __launch_bounds__(128) void k_meanmax(const float* __restrict__ O,
        const float* __restrict__ COS, const float* __restrict__ RS,
        const float* __restrict__ CS, float* __restrict__ MM) {
  int b = blockIdx.x, rg = blockIdx.y, v = blockIdx.z;
  int isMax = v >> 2, vv = v & 3;
  int d = vv & 1, s2side = vv >> 1;
  int srcrec = s2side ? 0 : 2;
  const float* SRC = O + ((size_t)srcrec * M_ + b * S_) * 300;
  const float* Cb = COS + ((size_t)d * 32 + b) * 4096;
  int tid = threadIdx.x;
  int h0 = tid, h1 = tid + 128, h2 = tid + 256;
  bool has2 = (h2 < 300);
  float init = isMax ? -INFINITY : 0.f;
  float acc[8][3];
  #pragma unroll
  for (int rr = 0; rr < 8; ++rr) { acc[rr][0] = init; acc[rr][1] = init; acc[rr][2] = init; }
  int r0 = rg * 8;
  for (int inner = 0; inner < 64; ++inner) {
    float s0 = SRC[(size_t)inner * 300 + h0];
    float s1 = SRC[(size_t)inner * 300 + h1];
    float s2v = has2 ? SRC[(size_t)inner * 300 + h2] : 0.f;
    #pragma unroll
    for (int rr = 0; rr < 8; ++rr) {
      int r = r0 + rr;
      float cv = s2side ? Cb[inner * 64 + r] : Cb[r * 64 + inner];
      if (isMax) {
        acc[rr][0] = fmaxf(acc[rr][0], cv * s0);
        acc[rr][1] = fmaxf(acc[rr][1], cv * s1);
        acc[rr][2] = fmaxf(acc[rr][2], cv * s2v);
      } else {
        acc[rr][0] += cv * s0; acc[rr][1] += cv * s1; acc[rr][2] += cv * s2v;
      }
    }
  }
  float* outp = MM + (size_t)v * 614400;
  for (int rr = 0; rr < 8; ++rr) {
    int r = r0 + rr;
    size_t o = ((size_t)b * S_ + r) * 300;
    if (isMax) {
      outp[o + h0] = acc[rr][0];
      outp[o + h1] = acc[rr][1];
      if (has2) outp[o + h2] = acc[rr][2];
    } else {
      float den = s2side ? CS[(d * 32 + b) * 64 + r] : RS[(d * 32 + b) * 64 + r];
      outp[o + h0] = acc[rr][0] / den;
      outp[o + h1] = acc[rr][1] / den;
      if (has2) outp[o + h2] = acc[rr][2] / den;
    }
  }
}

// ---------------- generic full-match (12 variants) ----------------
__global__ __launch_bounds__(256) void k_fullmatch(const float* __restrict__ O,
        const float* __restrict__ MM, const float* __restrict__ Wff,
        const float* __restrict__ Wfb, const float* __restrict__ Wat,
        const float* __restrict__ Wmx, float* __restrict__ V1, float* __restrict__ V2) {
  int item = blockIdx.x * 4 + (threadIdx.x >> 6);
  int lane = threadIdx.x & 63;
  int b = item >> 6, s = item & 63;
  int var = blockIdx.y;
  size_t ms = (size_t)b * S_ + s;
  const float* s1f = O;
  const float* s1b = O + (size_t)M_ * 300;
  const float* s2f = O + (size_t)2 * M_ * 300;
  const float* s2b = O + (size_t)3 * M_ * 300;
  const float *v1p, *v2p, *W;
  float* outp;
  switch (var) {
    case 0:  v1p = s1f + ms * 300; v2p = s2f + ((size_t)b * S_ + 63) * 300; W = Wff; outp = V1 + ms * 160 + 0;   break;
    case 1:  v1p = s1f + ms * 300; v2p = MM + (size_t)0 * 614400 + ms * 300; W = Wat; outp = V1 + ms * 160 + 40; break;
    case 2:  v1p = s1f + ms * 300; v2p = MM + (size_t)4 * 614400 + ms * 300; W = Wmx; outp = V1 + ms * 160 + 60; break;
    case 3:  v1p = s1b + ms * 300; v2p = s2b + ((size_t)b * S_ + 0) * 300;  W = Wfb; outp = V1 + ms * 160 + 80;  break;
    case 4:  v1p = s1b + ms * 300; v2p = MM + (size_t)1 * 614400 + ms * 300; W = Wat; outp = V1 + ms * 160 + 120; break;
    case 5:  v1p = s1b + ms * 300; v2p = MM + (size_t)5 * 614400 + ms * 300; W = Wmx; outp = V1 + ms * 160 + 140; break;
    case 6:  v1p = s2f + ms * 300; v2p = s1f + ((size_t)b * S_ + 63) * 300; W = Wff; outp = V2 + ms * 160 + 0;   break;
    case 7:  v1p = s2f + ms * 300; v2p = MM + (size_t)2 * 614400 + ms * 300; W = Wat; outp = V2 + ms * 160 + 40; break;
    case 8:  v1p = s2f + ms * 300; v2p = MM + (size_t)6 * 614400 + ms * 300; W = Wmx; outp = V2 + ms * 160 + 60; break;
    case 9:  v1p = s2b + ms * 300; v2p = s1b + ((size_t)b * S_ + 0) * 300;  W = Wfb; outp = V2 + ms * 160 + 80;  break;
    case 10: v1p = s2b + ms * 300; v2p = MM + (size_t)3 * 614400 + ms * 300; W = Wat; outp = V2 + ms * 160 + 120; break;
    default: v1p = s2b + ms * 300; v2p = MM + (size_t)7 * 614400 + ms * 300; W = Wmx; outp = V2 + ms * 160 + 140; break;
  }
  float av[5], bv[5], ab[5], a2[5], b2[5];
  #pragma unroll
  for (int q = 0; q < 5; ++q) {
    int h = lane + 64 * q;
    bool in = (h < 300);
    av[q] = in ? v1p[h] : 0.f;
    bv[q] = in ? v2p[h] : 0.f;
    ab[q] = av[q] * bv[q];
    a2[q] = av[q] * av[q];
    b2[q] = bv[q] * bv[q];
  }
  for (int lq = 0; lq < 20; ++lq) {
    float sn = 0.f, sa = 0.f, sb = 0.f;
    #pragma unroll
    for (int q = 0; q < 5; ++q) {
      int h = lane + 64 * q;
      if (h < 300) {
        float w = W[(size_t)lq * 300 + h];
        float w2 = w * w;
        sn += w2 * ab[q]; sa += w2 * a2[q]; sb += w2 * b2[q];
      }
    }
    #pragma unroll
    for (int off = 32; off; off >>= 1) {
      sn += __shfl_xor(sn, off);
      sa += __shfl_xor(sa, off);
      sb += __shfl_xor(sb, off);
    }
    if (lane == 0) {
      float n1 = fmaxf(sqrtf(sa), EPSF);
      float n2 = fmaxf(sqrtf(sb), EPSF);
      outp[lq] = sn / (n1 * n2);
    }
  }
}

// ---------------- final MLP + log_softmax ----------------
__global__ __launch_bounds__(256) void k_mlp(const f16* __restrict__ H16,
        const float* __restrict__ W1T, const float* __restrict__ b1,
        const float* __restrict__ W2, const float* __restrict__ b2,
        float* __restrict__ out) {
  int b = blockIdx.x, tid = threadIdx.x;
  __shared__ float mvs[1200];
  __shared__ float xs[600];
  __shared__ float red[2][4];
  for (int i = tid; i < 1200; i += 256) {
    int r = i / 300, h = i - r * 300;
    mvs[i] = (float)H16[((size_t)r * 32 + b) * 320 + h];
  }
  __syncthreads();
  for (int o = tid; o < 600; o += 256) {
    float dot = b1[o];
    for (int k = 0; k < 1200; ++k) dot += mvs[k] * W1T[(size_t)k * 600 + o];
    xs[o] = tanhf(dot);
  }
  __syncthreads();
  float p0 = 0.f, p1 = 0.f;
  for (int k = tid; k < 600; k += 256) {
    float xv = xs[k];
    p0 += xv * W2[k];
    p1 += xv * W2[600 + k];
  }
  #pragma unroll
  for (int off = 32; off; off >>= 1) { p0 += __shfl_xor(p0, off); p1 += __shfl_xor(p1, off); }
  int w = tid >> 6;
  if ((tid & 63) == 0) { red[0][w] = p0; red[1][w] = p1; }
  __syncthreads();
  if (tid == 0) {
    float l0 = red[0][0] + red[0][1] + red[0][2] + red[0][3] + b2[0];
    float l1 = red[1][0] + red[1][1] + red[1][2] + red[1][3] + b2[1];
    float m = fmaxf(l0, l1);
    float lse = m + logf(expf(l0 - m) + expf(l1 - m));
    out[b * 2 + 0] = l0 - lse;
    out[b * 2 + 1] = l1 - lse;
  }
}

extern "C" void kernel_launch(void* const* d_in, const int* in_sizes, int n_in,
                              void* d_out, int out_size, void* d_ws, size_t ws_size,
                              hipStream_t stream) {
  (void)in_sizes; (void)out_size;
  if (n_in < 25) return;
  const float* emb    = (const float*)d_in[0];
  const float* cWihF  = (const float*)d_in[1];
  const float* cWhhF  = (const float*)d_in[2];
  const float* cbF    = (const float*)d_in[3];
  const float* cWihB  = (const float*)d_in[4];
  const float* cWhhB  = (const float*)d_in[5];
  const float* cbB    = (const float*)d_in[6];
  const float* aWihF  = (const float*)d_in[7];
  const float* aWhhF  = (const float*)d_in[8];
  const float* abF    = (const float*)d_in[9];
  const float* aWihB  = (const float*)d_in[10];
  const float* aWhhB  = (const float*)d_in[11];
  const float* abB    = (const float*)d_in[12];
  const float* WfullF = (const float*)d_in[13];
  const float* WfullB = (const float*)d_in[14];
  const float* WmaxpF = (const float*)d_in[15];
  const float* WmaxpB = (const float*)d_in[16];
  const float* WattnF = (const float*)d_in[17];
  const float* WmaxaF = (const float*)d_in[18];
  const float* pW1    = (const float*)d_in[19];
  const float* pb1    = (const float*)d_in[20];
  const float* pW2    = (const float*)d_in[21];
  const float* pb2    = (const float*)d_in[22];
  const int*   sa     = (const int*)d_in[23];
  const int*   sb     = (const int*)d_in[24];
  float* out = (float*)d_out;
  float* ws = (float*)d_ws;

  // ---- workspace layout (float offsets) ----
  if (ws_size < (size_t)11298048 * 4) return;
  float* WT_cihF = ws + 0;          //  360000
  float* WT_cihB = ws + 360000;     //  360000
  float* WT_aihF = ws + 720000;     //  192000
  float* WT_aihB = ws + 912000;     //  192000
  float* W1T     = ws + 1104000;    //  720000
  f16*   Wh16    = (f16*)(ws + 1824000);   // 4*409600 f16 = 819200 fl
  f16*   Hfin    = (f16*)(ws + 2643200);   // 40960 f16 = 20480 fl
  float* NRM  = ws + 2663680;       //    8192
  float* COS  = ws + 2671872;       //  262144
  float* RS   = ws + 2934016;       //    4096
  float* CS   = ws + 2938112;       //    4096
  float* V1   = ws + 2942208;       //  327680
  float* V2   = ws + 3269888;       //  327680
  f16*   XG2  = (f16*)(ws + 3597568);      // 10485760 f16 = 5242880 fl
  float* MM   = ws + 3597568;       //  alias (4915200 <= 5242880)
  float* O    = ws + 8840448;       //  2457600

  f16* WhCtx = Wh16;
  f16* WhAgg = Wh16 + (size_t)2 * 409600;

  // ---- weight prep ----
  k_transpose<<<dim3(10, 38), 256, 0, stream>>>(cWihF, WT_cihF, 1200, 300);
  k_transpose<<<dim3(10, 38), 256, 0, stream>>>(cWihB, WT_cihB, 1200, 300);
  k_transpose<<<dim3(5, 38), 256, 0, stream>>>(aWihF, WT_aihF, 1200, 160);
  k_transpose<<<dim3(5, 38), 256, 0, stream>>>(aWihB, WT_aihB, 1200, 160);
  k_transpose<<<dim3(38, 19), 256, 0, stream>>>(pW1, W1T, 600, 1200);
  k_wh16<<<1600, 256, 0, stream>>>(cWhhF, WhCtx);
  k_wh16<<<1600, 256, 0, stream>>>(cWhhB, WhCtx + 409600);
  k_wh16<<<1600, 256, 0, stream>>>(aWhhF, WhAgg);
  k_wh16<<<1600, 256, 0, stream>>>(aWhhB, WhAgg + 409600);

  // ---- context BiLSTM ----
  k_proj<<<dim3(32, 19), 256, 0, stream>>>(emb, sa, WT_cihF, cbF, XG2, 1200, 300, 300, 0, 0);
  k_proj<<<dim3(32, 19), 256, 0, stream>>>(emb, sa, WT_cihB, cbB, XG2, 1200, 300, 300, 1, 1);
  k_proj<<<dim3(32, 19), 256, 0, stream>>>(emb, sb, WT_cihF, cbF, XG2, 1200, 300, 300, 2, 0);
  k_proj<<<dim3(32, 19), 256, 0, stream>>>(emb, sb, WT_cihB, cbB, XG2, 1200, 300, 300, 3, 1);
  k_lstm2<<<8, 640, 0, stream>>>(WhCtx, XG2, Hfin, O);

  // ---- matching ----
  k_norms<<<2048, 256, 0, stream>>>(O, NRM);
  k_cos<<<dim3(32, 2), 256, 0, stream>>>(O, NRM, COS);
  k_csum<<<dim3(32, 2), 64, 0, stream>>>(COS, RS, CS);
  k_pairfused<<<dim3(32, 20, 2), 256, 0, stream>>>(O, NRM, WmaxpF, WmaxpB, V1, V2);
  k_meanmax<<<dim3(32, 8, 8), 128, 0, stream>>>(O, COS, RS, CS, MM);
  k_fullmatch<<<dim3(512, 12), 256, 0, stream>>>(O, MM, WfullF, WfullB, WattnF, WmaxaF, V1, V2);

  // ---- aggregation BiLSTM ----
  k_proj<<<dim3(32, 19), 256, 0, stream>>>(V1, nullptr, WT_aihF, abF, XG2, 1200, 160, 160, 0, 0);
  k_proj<<<dim3(32, 19), 256, 0, stream>>>(V1, nullptr, WT_aihB, abB, XG2, 1200, 160, 160, 1, 1);
  k_proj<<<dim3(32, 19), 256, 0, stream>>>(V2, nullptr, WT_aihF, abF, XG2, 1200, 160, 160, 2, 0);
  k_proj<<<dim3(32, 19), 256, 0, stream>>>(V2, nullptr, WT_aihB, abB, XG2, 1200, 160, 160, 3, 1);
  k_lstm2<<<8, 640, 0, stream>>>(WhAgg, XG2, Hfin, nullptr);

  // ---- prediction head ----
  k_mlp<<<32, 256, 0, stream>>>(Hfin, W1T, pb1, pW2, pb2, out);
}

// Round 5
// 2712.523 us; speedup vs baseline: 1.5861x; 1.5861x over previous
//
#include <hip/hip_runtime.h>
#include <math.h>

#define B_ 32
#define S_ 64
#define H_ 300
#define M_ 2048          // B*S
#define EPSF 1e-8f

typedef _Float16 f16;
typedef _Float16 f16x2 __attribute__((ext_vector_type(2)));
typedef _Float16 f16x4 __attribute__((ext_vector_type(4)));
typedef _Float16 f16x8 __attribute__((ext_vector_type(8)));
typedef float f32x4 __attribute__((ext_vector_type(4)));

// ---------------- transpose (R x C) -> (C x R) ----------------
__global__ __launch_bounds__(256) void k_transpose(const float* __restrict__ src,
        float* __restrict__ dst, int R, int C) {
  __shared__ float t[32][33];
  int tx = threadIdx.x & 31, ty = threadIdx.x >> 5;
  int c0 = blockIdx.x * 32, r0 = blockIdx.y * 32;
  #pragma unroll
  for (int q = 0; q < 4; ++q) {
    int r = r0 + ty + q * 8, c = c0 + tx;
    t[ty + q * 8][tx] = (r < R && c < C) ? src[(size_t)r * C + c] : 0.f;
  }
  __syncthreads();
  #pragma unroll
  for (int q = 0; q < 4; ++q) {
    int c = c0 + ty + q * 8, r = r0 + tx;
    if (c < C && r < R) dst[(size_t)c * R + r] = t[tx][ty + q * 8];
  }
}

// ---- Whh (1200x300 f32) -> f16 padded [4 g][320 u][320 k], zeros outside ----
__global__ __launch_bounds__(256) void k_wh16(const float* __restrict__ W,
        f16* __restrict__ D) {
  int idx = blockIdx.x * 256 + threadIdx.x;
  if (idx >= 409600) return;
  int g = idx / 102400, rem = idx - g * 102400;
  int u = rem / 320, k = rem - u * 320;
  float v = (u < 300 && k < 300) ? W[((size_t)g * 300 + u) * 300 + k] : 0.f;
  D[idx] = (f16)v;
}

// ---------------- input-projection GEMM, scatter to f16 fragment layout ----
// z[m,n]=sum_k A[row(m),k]*WT[k,n]+bias[n] -> XG2 f16:
// off = ((((rec*64+t)*10+jb)*4+g)*2+nh)*512 + mt*256 + l*4 + r
// where b = mt*16 + hi*4 + r, l = hi*16+lo, u = jb*32 + nh*16 + lo
__global__ __launch_bounds__(256) void k_proj(const float* __restrict__ A,
        const int* __restrict__ gather, const float* __restrict__ WT,
        const float* __restrict__ bias, f16* __restrict__ XG2,
        int N, int K, int lda, int rec, int rev) {
  __shared__ float As[16][66];
  __shared__ float Bs[16][66];
  int tid = threadIdx.x;
  int m0 = blockIdx.x * 64, n0 = blockIdx.y * 64;
  int tx = tid & 15, ty = tid >> 4;
  int ar = tid >> 2, ac = (tid & 3) * 4;
  int br = tid >> 4, bc = (tid & 15) * 4;
  int gm = m0 + ar;
  const float* Arow = gather ? (A + (size_t)gather[gm] * lda)
                             : (A + (size_t)gm * lda);
  float acc[4][4] = {};
  int nk = (K + 15) / 16;
  for (int kc = 0; kc < nk; ++kc) {
    int k0 = kc * 16;
    if (k0 + 16 <= K) {
      float4 av = *(const float4*)(Arow + k0 + ac);
      As[ac + 0][ar] = av.x; As[ac + 1][ar] = av.y;
      As[ac + 2][ar] = av.z; As[ac + 3][ar] = av.w;
    } else {
      #pragma unroll
      for (int q = 0; q < 4; ++q) {
        int k = k0 + ac + q;
        As[ac + q][ar] = (k < K) ? Arow[k] : 0.f;
      }
    }
    {
      int kk = k0 + br, n = n0 + bc;
      if (kk < K && n + 3 < N) {
        float4 bv = *(const float4*)(WT + (size_t)kk * N + n);
        Bs[br][bc + 0] = bv.x; Bs[br][bc + 1] = bv.y;
        Bs[br][bc + 2] = bv.z; Bs[br][bc + 3] = bv.w;
      } else {
        #pragma unroll
        for (int q = 0; q < 4; ++q) {
          int n2 = n + q;
          Bs[br][bc + q] = (kk < K && n2 < N) ? WT[(size_t)kk * N + n2] : 0.f;
        }
      }
    }
    __syncthreads();
    #pragma unroll
    for (int kk = 0; kk < 16; ++kk) {
      float av[4], bv[4];
      #pragma unroll
      for (int i = 0; i < 4; ++i) av[i] = As[kk][ty * 4 + i];
      #pragma unroll
      for (int j = 0; j < 4; ++j) bv[j] = Bs[kk][tx * 4 + j];
      #pragma unroll
      for (int i = 0; i < 4; ++i)
        #pragma unroll
        for (int j = 0; j < 4; ++j) acc[i][j] += av[i] * bv[j];
    }
    __syncthreads();
  }
  #pragma unroll
  for (int i = 0; i < 4; ++i) {
    int m = m0 + ty * 4 + i;
    int b = m >> 6, s = m & 63;
    int t = rev ? 63 - s : s;
    int mt = b >> 4, bl = b & 15;
    int hi2 = bl >> 2, r2 = bl & 3;
    #pragma unroll
    for (int j = 0; j < 4; ++j) {
      int n = n0 + tx * 4 + j;
      if (n < N) {
        float v = acc[i][j] + bias[n];
        int g = n / 300, u = n - g * 300;
        int jb = u >> 5, ul = u & 31;
        int nh = ul >> 4, lo2 = ul & 15;
        size_t off = ((((size_t)(rec * 64 + t) * 10 + jb) * 4 + g) * 2 + nh) * 512
                     + mt * 256 + (hi2 * 16 + lo2) * 4 + r2;
        XG2[off] = (f16)v;
      }
    }
  }
}

// ---------------- distributed MFMA LSTM: 40 blocks = 4 rec x 10 u-tiles ----
// 8 waves/block: wave = (g = w&3, nh = w>>2). Weight frags register-resident
// (40 VGPR). h exchanged per step via global Hbuf (parity dbuf) with the
// validated fence+counter protocol; staged to LDS each step.
__global__ __launch_bounds__(512, 1) void k_lstm3(
    const f16* __restrict__ Wh, const f16* __restrict__ XG2,
    f16* __restrict__ Hbuf, float* __restrict__ O,
    unsigned int* __restrict__ cnt) {
  int bid = blockIdx.x;
  int rec = bid / 10, jb = bid - rec * 10;
  int tid = threadIdx.x;
  int w = tid >> 6, l = tid & 63, lo = l & 15, hi = l >> 4;
  int g = w & 3, nh = w >> 2;

  __shared__ f16 Hs[32][328];          // padded stride vs bank conflicts
  __shared__ float zs[4][32][33];

  // register-resident weight fragments for this wave's (g, u-tile, nh)
  const f16* Wd = Wh + (size_t)(rec & 1) * 409600;
  int u_t = jb * 32 + nh * 16 + lo;
  f16x8 Bf[10];
  #pragma unroll
  for (int kt = 0; kt < 10; ++kt)
    Bf[kt] = *(const f16x8*)(Wd + ((size_t)g * 320 + u_t) * 320 + kt * 32 + hi * 8);

  // combine-phase mapping: thread -> (b, u-pair)
  int cb = tid >> 4, cup = tid & 15;
  int u0c = jb * 32 + cup * 2;
  float c0 = 0.f, c1 = 0.f;
  unsigned int* cp = cnt + rec;
  const f16* xgbase = XG2 + ((size_t)(rec * 64) * 10 + jb) * 4096
                      + ((size_t)(g * 2 + nh)) * 512 + l * 4;

  for (int t = 0; t < 64; ++t) {
    if (t > 0) {
      if (tid == 0) {
        while (__hip_atomic_load(cp, __ATOMIC_ACQUIRE, __HIP_MEMORY_SCOPE_AGENT)
               < 10u * (unsigned)t)
          __builtin_amdgcn_s_sleep(2);
      }
      __syncthreads();
      __threadfence();                 // acquire: fresh reads of Hbuf
    }
    // stage h_t (20 KB) global -> LDS, coalesced u32
    {
      const float* Hg = (const float*)(Hbuf + ((size_t)(t & 1) * 4 + rec) * 10240);
      #pragma unroll
      for (int q = 0; q < 10; ++q) {
        int idx = q * 512 + tid;       // 0..5119 u32
        int b = idx / 160, rm = idx - b * 160;
        *(float*)(&Hs[b][rm * 2]) = Hg[idx];
      }
    }
    __syncthreads();

    // z = Whh_g . h  (per wave: 2 mt x 10 kt MFMAs) + xg
    const f16* xt = xgbase + (size_t)t * 40960;
    f32x4 acc[2] = {};
    #pragma unroll
    for (int kt = 0; kt < 10; ++kt) {
      #pragma unroll
      for (int mt = 0; mt < 2; ++mt) {
        f16x8 Af = *(const f16x8*)(&Hs[mt * 16 + lo][kt * 32 + hi * 8]);
        acc[mt] = __builtin_amdgcn_mfma_f32_16x16x32_f16(Af, Bf[kt], acc[mt], 0, 0, 0);
      }
    }
    #pragma unroll
    for (int mt = 0; mt < 2; ++mt) {
      f16x4 xv = *(const f16x4*)(xt + mt * 256);
      #pragma unroll
      for (int r = 0; r < 4; ++r)
        zs[g][mt * 16 + hi * 4 + r][nh * 16 + lo] = acc[mt][r] + (float)xv[r];
    }
    __syncthreads();

    // gates: thread owns (b=cb, u = u0c, u0c+1)
    int tt = (rec & 1) ? 63 - t : t;
    float h0n, h1n;
    {
      int uu = cup * 2;
      float zi = zs[0][cb][uu], zf = zs[1][cb][uu];
      float zg = zs[2][cb][uu], zo = zs[3][cb][uu];
      float si = 1.f / (1.f + expf(-zi));
      float sf = 1.f / (1.f + expf(-zf));
      float so = 1.f / (1.f + expf(-zo));
      float cn = sf * c0 + si * tanhf(zg);
      h0n = so * tanhf(cn);
      c0 = cn;
      zi = zs[0][cb][uu + 1]; zf = zs[1][cb][uu + 1];
      zg = zs[2][cb][uu + 1]; zo = zs[3][cb][uu + 1];
      si = 1.f / (1.f + expf(-zi));
      sf = 1.f / (1.f + expf(-zf));
      so = 1.f / (1.f + expf(-zo));
      cn = sf * c1 + si * tanhf(zg);
      h1n = so * tanhf(cn);
      c1 = cn;
    }
    if (u0c >= 300) { h0n = 0.f; h1n = 0.f; }   // pad lanes exact zero
    f16x2 hp; hp[0] = (f16)h0n; hp[1] = (f16)h1n;
    f16x2* Hw = (f16x2*)(Hbuf + ((size_t)((t + 1) & 1) * 4 + rec) * 10240);
    Hw[cb * 160 + jb * 16 + cup] = hp;
    if (O && u0c < 300) {
      float2 ov; ov.x = h0n; ov.y = h1n;
      *(float2*)(O + ((size_t)rec * 2048 + cb * 64 + tt) * 300 + u0c) = ov;
    }
    __threadfence();                   // release: h visible device-wide
    __syncthreads();
    if (tid == 0) atomicAdd(cp, 1u);
  }
}

// ---------------- plain L2 norms of the 4 ctx outputs ----------------
__global__ __launch_bounds__(256) void k_norms(const float* __restrict__ O,
        float* __restrict__ NRM) {
  int idx = blockIdx.x * 4 + (threadIdx.x >> 6);
  int lane = threadIdx.x & 63;
  const float* p = O + (size_t)idx * 300;
  float s = 0.f;
  for (int h = lane; h < 300; h += 64) { float v = p[h]; s += v * v; }
  #pragma unroll
  for (int off = 32; off; off >>= 1) s += __shfl_xor(s, off);
  if (lane == 0) NRM[idx] = sqrtf(s);
}

// ---------------- cosine matrices ----------------
__global__ __launch_bounds__(256) void k_cos(const float* __restrict__ O,
        const float* __restrict__ NRM, float* __restrict__ COS) {
  int b = blockIdx.x, d = blockIdx.y;
  int r1 = d, r2 = 2 + d;
  const float* A = O + ((size_t)r1 * M_ + b * S_) * 300;
  const float* Bm = O + ((size_t)r2 * M_ + b * S_) * 300;
  __shared__ float As[64][33], Bs[64][33];
  int tid = threadIdx.x;
  int tx = tid & 15, ty = tid >> 4;
  int lr = tid >> 2, lc = (tid & 3) * 8;
  float acc[4][4] = {};
  for (int k0 = 0; k0 < 300; k0 += 32) {
    if (k0 + 32 <= 300) {
      float4 a0 = *(const float4*)(A + (size_t)lr * 300 + k0 + lc);
      float4 a1 = *(const float4*)(A + (size_t)lr * 300 + k0 + lc + 4);
      As[lr][lc + 0] = a0.x; As[lr][lc + 1] = a0.y; As[lr][lc + 2] = a0.z; As[lr][lc + 3] = a0.w;
      As[lr][lc + 4] = a1.x; As[lr][lc + 5] = a1.y; As[lr][lc + 6] = a1.z; As[lr][lc + 7] = a1.w;
      float4 b0 = *(const float4*)(Bm + (size_t)lr * 300 + k0 + lc);
      float4 b1 = *(const float4*)(Bm + (size_t)lr * 300 + k0 + lc + 4);
      Bs[lr][lc + 0] = b0.x; Bs[lr][lc + 1] = b0.y; Bs[lr][lc + 2] = b0.z; Bs[lr][lc + 3] = b0.w;
      Bs[lr][lc + 4] = b1.x; Bs[lr][lc + 5] = b1.y; Bs[lr][lc + 6] = b1.z; Bs[lr][lc + 7] = b1.w;
    } else {
      #pragma unroll
      for (int q = 0; q < 8; ++q) {
        int k = k0 + lc + q;
        As[lr][lc + q] = (k < 300) ? A[(size_t)lr * 300 + k] : 0.f;
        Bs[lr][lc + q] = (k < 300) ? Bm[(size_t)lr * 300 + k] : 0.f;
      }
    }
    __syncthreads();
    #pragma unroll
    for (int kk = 0; kk < 32; ++kk) {
      float av[4], bv[4];
      #pragma unroll
      for (int i = 0; i < 4; ++i) av[i] = As[ty * 4 + i][kk];
      #pragma unroll
      for (int j = 0; j < 4; ++j) bv[j] = Bs[tx * 4 + j][kk];
      #pragma unroll
      for (int i = 0; i < 4; ++i)
        #pragma unroll
        for (int j = 0; j < 4; ++j) acc[i][j] += av[i] * bv[j];
    }
    __syncthreads();
  }
  float n1[4], n2[4];
  #pragma unroll
  for (int i = 0; i < 4; ++i) {
    n1[i] = NRM[(size_t)r1 * M_ + b * S_ + ty * 4 + i];
    n2[i] = NRM[(size_t)r2 * M_ + b * S_ + tx * 4 + i];
  }
  float* outp = COS + ((size_t)d * 32 + b) * 4096;
  #pragma unroll
  for (int i = 0; i < 4; ++i)
    #pragma unroll
    for (int j = 0; j < 4; ++j)
      outp[(ty * 4 + i) * 64 + tx * 4 + j] = acc[i][j] / (n1[i] * n2[j]);
}

// ---------------- cos row/col sums ----------------
__global__ __launch_bounds__(64) void k_csum(const float* __restrict__ COS,
        float* __restrict__ RS, float* __restrict__ CS) {
  int b = blockIdx.x, d = blockIdx.y, t = threadIdx.x;
  const float* base = COS + ((size_t)d * 32 + b) * 4096;
  float rs = 0.f, cs = 0.f;
  for (int k = 0; k < 64; ++k) { rs += base[t * 64 + k]; cs += base[k * 64 + t]; }
  RS[(d * 32 + b) * 64 + t] = rs;
  CS[(d * 32 + b) * 64 + t] = cs;
}

// ---- pairwise match + fused max over i and j (PAIR never materialized) ----
__global__ __launch_bounds__(256) void k_pairfused(const float* __restrict__ O,
        const float* __restrict__ NRM, const float* __restrict__ Wf,
        const float* __restrict__ Wb, float* __restrict__ V1, float* __restrict__ V2) {
  int b = blockIdx.x, lidx = blockIdx.y, d = blockIdx.z;
  int r1 = d;
  const float* A = O + ((size_t)r1 * M_ + b * S_) * 300;
  const float* Bm = O + ((size_t)3 * M_ + b * S_) * 300;
  const float* Wl = (d ? Wb : Wf) + (size_t)lidx * 300;
  __shared__ float As[64][33], Bs[64][33];
  int tid = threadIdx.x;
  int tx = tid & 15, ty = tid >> 4;
  int lr = tid >> 2, lc = (tid & 3) * 8;
  float acc[4][4] = {};
  for (int k0 = 0; k0 < 300; k0 += 32) {
    if (k0 + 32 <= 300) {
      float4 a0 = *(const float4*)(A + (size_t)lr * 300 + k0 + lc);
      float4 a1 = *(const float4*)(A + (size_t)lr * 300 + k0 + lc + 4);
      float4 w0 = *(const float4*)(Wl + k0 + lc);
      float4 w1 = *(const float4*)(Wl + k0 + lc + 4);
      As[lr][lc + 0] = a0.x * w0.x * w0.x; As[lr][lc + 1] = a0.y * w0.y * w0.y;
      As[lr][lc + 2] = a0.z * w0.z * w0.z; As[lr][lc + 3] = a0.w * w0.w * w0.w;
      As[lr][lc + 4] = a1.x * w1.x * w1.x; As[lr][lc + 5] = a1.y * w1.y * w1.y;
      As[lr][lc + 6] = a1.z * w1.z * w1.z; As[lr][lc + 7] = a1.w * w1.w * w1.w;
      float4 b0 = *(const float4*)(Bm + (size_t)lr * 300 + k0 + lc);
      float4 b1 = *(const float4*)(Bm + (size_t)lr * 300 + k0 + lc + 4);
      Bs[lr][lc + 0] = b0.x; Bs[lr][lc + 1] = b0.y; Bs[lr][lc + 2] = b0.z; Bs[lr][lc + 3] = b0.w;
      Bs[lr][lc + 4] = b1.x; Bs[lr][lc + 5] = b1.y; Bs[lr][lc + 6] = b1.z; Bs[lr][lc + 7] = b1.w;
    } else {
      #pragma unroll
      for (int q = 0; q < 8; ++q) {
        int k = k0 + lc + q;
        float w = (k < 300) ? Wl[k] : 0.f;
        As[lr][lc + q] = (k < 300) ? A[(size_t)lr * 300 + k] * w * w : 0.f;
        Bs[lr][lc + q] = (k < 300) ? Bm[(size_t)lr * 300 + k] : 0.f;
      }
    }
    __syncthreads();
    #pragma unroll
    for (int kk = 0; kk < 32; ++kk) {
      float av[4], bv[4];
      #pragma unroll
      for (int i = 0; i < 4; ++i) av[i] = As[ty * 4 + i][kk];
      #pragma unroll
      for (int j = 0; j < 4; ++j) bv[j] = Bs[tx * 4 + j][kk];
      #pragma unroll
      for (int i = 0; i < 4; ++i)
        #pragma unroll
        for (int j = 0; j < 4; ++j) acc[i][j] += av[i] * bv[j];
    }
    __syncthreads();
  }
  float n1[4], n2[4];
  #pragma unroll
  for (int i = 0; i < 4; ++i) {
    n1[i] = NRM[(size_t)r1 * M_ + b * S_ + ty * 4 + i];
    n2[i] = NRM[(size_t)3 * M_ + b * S_ + tx * 4 + i];
  }
  int offv = (d ? 100 : 20) + lidx;
  float mj[4], mi[4];
  #pragma unroll
  for (int q = 0; q < 4; ++q) { mj[q] = -INFINITY; mi[q] = -INFINITY; }
  #pragma unroll
  for (int i = 0; i < 4; ++i)
    #pragma unroll
    for (int j = 0; j < 4; ++j) {
      float v = acc[i][j] / (n1[i] * n2[j]);
      mj[i] = fmaxf(mj[i], v);
      mi[j] = fmaxf(mi[j], v);
    }
  #pragma unroll
  for (int off = 1; off < 16; off <<= 1)
    #pragma unroll
    for (int i = 0; i < 4; ++i) mj[i] = fmaxf(mj[i], __shfl_xor(mj[i], off));
  if (tx == 0)
    #pragma unroll
    for (int i = 0; i < 4; ++i)
      V1[((size_t)b * S_ + ty * 4 + i) * 160 + offv] = mj[i];
  float* red = &As[0][0];
  __syncthreads();
  #pragma unroll
  for (int j = 0; j < 4; ++j) red[(tx * 4 + j) * 16 + ty] = mi[j];
  __syncthreads();
  if (tid < 64) {
    float m = red[tid * 16];
    #pragma unroll
    for (int yy = 1; yy < 16; ++yy) m = fmaxf(m, red[tid * 16 + yy]);
    V2[((size_t)b * S_ + tid) * 160 + offv] = m;
  }
}

// ---------------- mean/max attention vectors MM[v][b][r][h] ----------------
__global__ __launch_bounds__(128) void k_meanmax(const float* __restrict__ O,
        const float* __restrict__ COS, const float* __restrict__ RS,
        const float* __restrict__ CS, float* __restrict__ MM) {
  int b = blockIdx.x, rg = blockIdx.y, v = blockIdx.z;
  int isMax = v >> 2, vv = v & 3;
  int d = vv & 1, s2side = vv >> 1;
  int srcrec = s2side ? 0 : 2;
  const float* SRC = O + ((size_t)srcrec * M_ + b * S_) * 300;
  const float* Cb = COS + ((size_t)d * 32 + b) * 4096;
  int tid = threadIdx.x;
  int h0 = tid, h1 = tid + 128, h2 = tid + 256;
  bool has2 = (h2 < 300);
  float init = isMax ? -INFINITY : 0.f;
  float acc[8][3];
  #pragma unroll
  for (int rr = 0; rr < 8; ++rr) { acc[rr][0] = init; acc[rr][1] = init; acc[rr][2] = init; }
  int r0 = rg * 8;
  for (int inner = 0; inner < 64; ++inner) {
    float s0 = SRC[(size_t)inner * 300 + h0];
    float s1 = SRC[(size_t)inner * 300 + h1];
    float s2v = has2 ? SRC[(size_t)inner * 300 + h2] : 0.f;
    #pragma unroll
    for (int rr = 0; rr < 8; ++rr) {
      int r = r0 + rr;
      float cv = s2side ? Cb[inner * 64 + r] : Cb[r * 64 + inner];
      if (isMax) {
        acc[rr][0] = fmaxf(acc[rr][0], cv * s0);
        acc[rr][1] = fmaxf(acc[rr][1], cv * s1);
        acc[rr][2] = fmaxf(acc[rr][2], cv * s2v);
      } else {
        acc[rr][0] += cv * s0; acc[rr][1] += cv * s1; acc[rr][2] += cv * s2v;
      }
    }
  }
  float* outp = MM + (size_t)v * 614400;
  for (int rr = 0; rr < 8; ++rr) {
    int r = r0 + rr;
    size_t o = ((size_t)b * S_ + r) * 300;
    if (isMax) {
      outp[o + h0] = acc[rr][0];
      outp[o + h1] = acc[rr][1];
      if (has2) outp[o + h2] = acc[rr][2];
    } else {
      float den = s2side ? CS[(d * 32 + b) * 64 + r] : RS[(d * 32 + b) * 64 + r];
      outp[o + h0] = acc[rr][0] / den;
      outp[o + h1] = acc[rr][1] / den;
      if (has2) outp[o + h2] = acc[rr][2] / den;
    }
  }
}

// ---------------- generic full-match (12 variants) ----------------
__global__ __launch_bounds__(256) void k_fullmatch(const float* __restrict__ O,
        const float* __restrict__ MM, const float* __restrict__ Wff,
        const float* __restrict__ Wfb, const float* __restrict__ Wat,
        const float* __restrict__ Wmx, float* __restrict__ V1, float* __restrict__ V2) {
  int item = blockIdx.x * 4 + (threadIdx.x >> 6);
  int lane = threadIdx.x & 63;
  int b = item >> 6, s = item & 63;
  int var = blockIdx.y;
  size_t ms = (size_t)b * S_ + s;
  const float* s1f = O;
  const float* s1b = O + (size_t)M_ * 300;
  const float* s2f = O + (size_t)2 * M_ * 300;
  const float* s2b = O + (size_t)3 * M_ * 300;
  const float *v1p, *v2p, *W;
  float* outp;
  switch (var) {
    case 0:  v1p = s1f + ms * 300; v2p = s2f + ((size_t)b * S_ + 63) * 300; W = Wff; outp = V1 + ms * 160 + 0;   break;
    case 1:  v1p = s1f + ms * 300; v2p = MM + (size_t)0 * 614400 + ms * 300; W = Wat; outp = V1 + ms * 160 + 40; break;
    case 2:  v1p = s1f + ms * 300; v2p = MM + (size_t)4 * 614400 + ms * 300; W = Wmx; outp = V1 + ms * 160 + 60; break;
    case 3:  v1p = s1b + ms * 300; v2p = s2b + ((size_t)b * S_ + 0) * 300;  W = Wfb; outp = V1 + ms * 160 + 80;  break;
    case 4:  v1p = s1b + ms * 300; v2p = MM + (size_t)1 * 614400 + ms * 300; W = Wat; outp = V1 + ms * 160 + 120; break;
    case 5:  v1p = s1b + ms * 300; v2p = MM + (size_t)5 * 614400 + ms * 300; W = Wmx; outp = V1 + ms * 160 + 140; break;
    case 6:  v1p = s2f + ms * 300; v2p = s1f + ((size_t)b * S_ + 63) * 300; W = Wff; outp = V2 + ms * 160 + 0;   break;
    case 7:  v1p = s2f + ms * 300; v2p = MM + (size_t)2 * 614400 + ms * 300; W = Wat; outp = V2 + ms * 160 + 40; break;
    case 8:  v1p = s2f + ms * 300; v2p = MM + (size_t)6 * 614400 + ms * 300; W = Wmx; outp = V2 + ms * 160 + 60; break;
    case 9:  v1p = s2b + ms * 300; v2p = s1b + ((size_t)b * S_ + 0) * 300;  W = Wfb; outp = V2 + ms * 160 + 80;  break;
    case 10: v1p = s2b + ms * 300; v2p = MM + (size_t)3 * 614400 + ms * 300; W = Wat; outp = V2 + ms * 160 + 120; break;
    default: v1p = s2b + ms * 300; v2p = MM + (size_t)7 * 614400 + ms * 300; W = Wmx; outp = V2 + ms * 160 + 140; break;
  }
  float av[5], bv[5], ab[5], a2[5], b2[5];
  #pragma unroll
  for (int q = 0; q < 5; ++q) {
    int h = lane + 64 * q;
    bool in = (h < 300);
    av[q] = in ? v1p[h] : 0.f;
    bv[q] = in ? v2p[h] : 0.f;
    ab[q] = av[q] * bv[q];
    a2[q] = av[q] * av[q];
    b2[q] = bv[q] * bv[q];
  }
  for (int lq = 0; lq < 20; ++lq) {
    float sn = 0.f, sa = 0.f, sb = 0.f;
    #pragma unroll
    for (int q = 0; q < 5; ++q) {
      int h = lane + 64 * q;
      if (h < 300) {
        float w = W[(size_t)lq * 300 + h];
        float w2 = w * w;
        sn += w2 * ab[q]; sa += w2 * a2[q]; sb += w2 * b2[q];
      }
    }
    #pragma unroll
    for (int off = 32; off; off >>= 1) {
      sn += __shfl_xor(sn, off);
      sa += __shfl_xor(sa, off);
      sb += __shfl_xor(sb, off);
    }
    if (lane == 0) {
      float n1 = fmaxf(sqrtf(sa), EPSF);
      float n2 = fmaxf(sqrtf(sb), EPSF);
      outp[lq] = sn / (n1 * n2);
    }
  }
}

// ---------------- final MLP + log_softmax ----------------
__global__ __launch_bounds__(256) void k_mlp(const f16* __restrict__ H16,
        const float* __restrict__ W1T, const float* __restrict__ b1,
        const float* __restrict__ W2, const float* __restrict__ b2,
        float* __restrict__ out) {
  int b = blockIdx.x, tid = threadIdx.x;
  __shared__ float mvs[1200];
  __shared__ float xs[600];
  __shared__ float red[2][4];
  for (int i = tid; i < 1200; i += 256) {
    int r = i / 300, h = i - r * 300;
    mvs[i] = (float)H16[((size_t)r * 32 + b) * 320 + h];
  }
  __syncthreads();
  for (int o = tid; o < 600; o += 256) {
    float dot = b1[o];
    for (int k = 0; k < 1200; ++k) dot += mvs[k] * W1T[(size_t)k * 600 + o];
    xs[o] = tanhf(dot);
  }
  __syncthreads();
  float p0 = 0.f, p1 = 0.f;
  for (int k = tid; k < 600; k += 256) {
    float xv = xs[k];
    p0 += xv * W2[k];
    p1 += xv * W2[600 + k];
  }
  #pragma unroll
  for (int off = 32; off; off >>= 1) { p0 += __shfl_xor(p0, off); p1 += __shfl_xor(p1, off); }
  int w = tid >> 6;
  if ((tid & 63) == 0) { red[0][w] = p0; red[1][w] = p1; }
  __syncthreads();
  if (tid == 0) {
    float l0 = red[0][0] + red[0][1] + red[0][2] + red[0][3] + b2[0];
    float l1 = red[1][0] + red[1][1] + red[1][2] + red[1][3] + b2[1];
    float m = fmaxf(l0, l1);
    float lse = m + logf(expf(l0 - m) + expf(l1 - m));
    out[b * 2 + 0] = l0 - lse;
    out[b * 2 + 1] = l1 - lse;
  }
}

extern "C" void kernel_launch(void* const* d_in, const int* in_sizes, int n_in,
                              void* d_out, int out_size, void* d_ws, size_t ws_size,
                              hipStream_t stream) {
  (void)in_sizes; (void)out_size;
  if (n_in < 25) return;
  const float* emb    = (const float*)d_in[0];
  const float* cWihF  = (const float*)d_in[1];
  const float* cWhhF  = (const float*)d_in[2];
  const float* cbF    = (const float*)d_in[3];
  const float* cWihB  = (const float*)d_in[4];
  const float* cWhhB  = (const float*)d_in[5];
  const float* cbB    = (const float*)d_in[6];
  const float* aWihF  = (const float*)d_in[7];
  const float* aWhhF  = (const float*)d_in[8];
  const float* abF    = (const float*)d_in[9];
  const float* aWihB  = (const float*)d_in[10];
  const float* aWhhB  = (const float*)d_in[11];
  const float* abB    = (const float*)d_in[12];
  const float* WfullF = (const float*)d_in[13];
  const float* WfullB = (const float*)d_in[14];
  const float* WmaxpF = (const float*)d_in[15];
  const float* WmaxpB = (const float*)d_in[16];
  const float* WattnF = (const float*)d_in[17];
  const float* WmaxaF = (const float*)d_in[18];
  const float* pW1    = (const float*)d_in[19];
  const float* pb1    = (const float*)d_in[20];
  const float* pW2    = (const float*)d_in[21];
  const float* pb2    = (const float*)d_in[22];
  const int*   sa     = (const int*)d_in[23];
  const int*   sb     = (const int*)d_in[24];
  float* out = (float*)d_out;
  float* ws = (float*)d_ws;

  // ---- workspace layout (float offsets) ----
  if (ws_size < (size_t)11318592 * 4) return;
  float* WT_cihF = ws + 0;          //  360000
  float* WT_cihB = ws + 360000;     //  360000
  float* WT_aihF = ws + 720000;     //  192000
  float* WT_aihB = ws + 912000;     //  192000
  float* W1T     = ws + 1104000;    //  720000
  f16*   Wh16    = (f16*)(ws + 1824000);   // 4*409600 f16 = 819200 fl
  f16*   Hbuf    = (f16*)(ws + 2643200);   // 2 par x 40960 f16 = 40960 fl
  unsigned int* cnt = (unsigned int*)(ws + 2684160);  // 64 fl
  float* NRM  = ws + 2684224;       //    8192
  float* COS  = ws + 2692416;       //  262144
  float* RS   = ws + 2954560;       //    4096
  float* CS   = ws + 2958656;       //    4096
  float* V1   = ws + 2962752;       //  327680
  float* V2   = ws + 3290432;       //  327680
  f16*   XG2  = (f16*)(ws + 3618112);      // 10485760 f16 = 5242880 fl
  float* MM   = ws + 3618112;       //  alias (4915200 <= 5242880)
  float* O    = ws + 8860992;       //  2457600

  f16* WhCtx = Wh16;
  f16* WhAgg = Wh16 + (size_t)2 * 409600;

  // ---- weight prep ----
  k_transpose<<<dim3(10, 38), 256, 0, stream>>>(cWihF, WT_cihF, 1200, 300);
  k_transpose<<<dim3(10, 38), 256, 0, stream>>>(cWihB, WT_cihB, 1200, 300);
  k_transpose<<<dim3(5, 38), 256, 0, stream>>>(aWihF, WT_aihF, 1200, 160);
  k_transpose<<<dim3(5, 38), 256, 0, stream>>>(aWihB, WT_aihB, 1200, 160);
  k_transpose<<<dim3(38, 19), 256, 0, stream>>>(pW1, W1T, 600, 1200);
  k_wh16<<<1600, 256, 0, stream>>>(cWhhF, WhCtx);
  k_wh16<<<1600, 256, 0, stream>>>(cWhhB, WhCtx + 409600);
  k_wh16<<<1600, 256, 0, stream>>>(aWhhF, WhAgg);
  k_wh16<<<1600, 256, 0, stream>>>(aWhhB, WhAgg + 409600);

  // ---- context BiLSTM ----
  k_proj<<<dim3(32, 19), 256, 0, stream>>>(emb, sa, WT_cihF, cbF, XG2, 1200, 300, 300, 0, 0);
  k_proj<<<dim3(32, 19), 256, 0, stream>>>(emb, sa, WT_cihB, cbB, XG2, 1200, 300, 300, 1, 1);
  k_proj<<<dim3(32, 19), 256, 0, stream>>>(emb, sb, WT_cihF, cbF, XG2, 1200, 300, 300, 2, 0);
  k_proj<<<dim3(32, 19), 256, 0, stream>>>(emb, sb, WT_cihB, cbB, XG2, 1200, 300, 300, 3, 1);
  hipMemsetAsync(Hbuf, 0, 81920, stream);              // parity-0 h = 0
  hipMemsetAsync(cnt, 0, 256, stream);
  k_lstm3<<<40, 512, 0, stream>>>(WhCtx, XG2, Hbuf, O, cnt);

  // ---- matching ----
  k_norms<<<2048, 256, 0, stream>>>(O, NRM);
  k_cos<<<dim3(32, 2), 256, 0, stream>>>(O, NRM, COS);
  k_csum<<<dim3(32, 2), 64, 0, stream>>>(COS, RS, CS);
  k_pairfused<<<dim3(32, 20, 2), 256, 0, stream>>>(O, NRM, WmaxpF, WmaxpB, V1, V2);
  k_meanmax<<<dim3(32, 8, 8), 128, 0, stream>>>(O, COS, RS, CS, MM);
  k_fullmatch<<<dim3(512, 12), 256, 0, stream>>>(O, MM, WfullF, WfullB, WattnF, WmaxaF, V1, V2);

  // ---- aggregation BiLSTM ----
  k_proj<<<dim3(32, 19), 256, 0, stream>>>(V1, nullptr, WT_aihF, abF, XG2, 1200, 160, 160, 0, 0);
  k_proj<<<dim3(32, 19), 256, 0, stream>>>(V1, nullptr, WT_aihB, abB, XG2, 1200, 160, 160, 1, 1);
  k_proj<<<dim3(32, 19), 256, 0, stream>>>(V2, nullptr, WT_aihF, abF, XG2, 1200, 160, 160, 2, 0);
  k_proj<<<dim3(32, 19), 256, 0, stream>>>(V2, nullptr, WT_aihB, abB, XG2, 1200, 160, 160, 3, 1);
  hipMemsetAsync(Hbuf, 0, 81920, stream);
  hipMemsetAsync(cnt, 0, 256, stream);
  k_lstm3<<<40, 512, 0, stream>>>(WhAgg, XG2, Hbuf, nullptr, cnt);

  // ---- prediction head ----
  k_mlp<<<32, 256, 0, stream>>>((f16*)(ws + 2643200), W1T, pb1, pW2, pb2, out);
}

// Round 6
// 1287.362 us; speedup vs baseline: 3.3419x; 2.1070x over previous
//
#include <hip/hip_runtime.h>
#include <math.h>

#define B_ 32
#define S_ 64
#define H_ 300
#define M_ 2048          // B*S
#define EPSF 1e-8f

typedef _Float16 f16;
typedef _Float16 f16x2 __attribute__((ext_vector_type(2)));
typedef _Float16 f16x4 __attribute__((ext_vector_type(4)));
typedef _Float16 f16x8 __attribute__((ext_vector_type(8)));
typedef float f32x4 __attribute__((ext_vector_type(4)));

// ---------------- transpose (R x C) -> (C x R) ----------------
__global__ __launch_bounds__(256) void k_transpose(const float* __restrict__ src,
        float* __restrict__ dst, int R, int C) {
  __shared__ float t[32][33];
  int tx = threadIdx.x & 31, ty = threadIdx.x >> 5;
  int c0 = blockIdx.x * 32, r0 = blockIdx.y * 32;
  #pragma unroll
  for (int q = 0; q < 4; ++q) {
    int r = r0 + ty + q * 8, c = c0 + tx;
    t[ty + q * 8][tx] = (r < R && c < C) ? src[(size_t)r * C + c] : 0.f;
  }
  __syncthreads();
  #pragma unroll
  for (int q = 0; q < 4; ++q) {
    int c = c0 + ty + q * 8, r = r0 + tx;
    if (c < C && r < R) dst[(size_t)c * R + r] = t[tx][ty + q * 8];
  }
}

// ---- Whh (1200x300 f32) -> f16 padded [4 g][320 u][320 k], zeros outside ----
__global__ __launch_bounds__(256) void k_wh16(const float* __restrict__ W,
        f16* __restrict__ D) {
  int idx = blockIdx.x * 256 + threadIdx.x;
  if (idx >= 409600) return;
  int g = idx / 102400, rem = idx - g * 102400;
  int u = rem / 320, k = rem - u * 320;
  float v = (u < 300 && k < 300) ? W[((size_t)g * 300 + u) * 300 + k] : 0.f;
  D[idx] = (f16)v;
}

// ---------------- input-projection GEMM, scatter to f16 fragment layout ----
__global__ __launch_bounds__(256) void k_proj(const float* __restrict__ A,
        const int* __restrict__ gather, const float* __restrict__ WT,
        const float* __restrict__ bias, f16* __restrict__ XG2,
        int N, int K, int lda, int rec, int rev) {
  __shared__ float As[16][66];
  __shared__ float Bs[16][66];
  int tid = threadIdx.x;
  int m0 = blockIdx.x * 64, n0 = blockIdx.y * 64;
  int tx = tid & 15, ty = tid >> 4;
  int ar = tid >> 2, ac = (tid & 3) * 4;
  int br = tid >> 4, bc = (tid & 15) * 4;
  int gm = m0 + ar;
  const float* Arow = gather ? (A + (size_t)gather[gm] * lda)
                             : (A + (size_t)gm * lda);
  float acc[4][4] = {};
  int nk = (K + 15) / 16;
  for (int kc = 0; kc < nk; ++kc) {
    int k0 = kc * 16;
    if (k0 + 16 <= K) {
      float4 av = *(const float4*)(Arow + k0 + ac);
      As[ac + 0][ar] = av.x; As[ac + 1][ar] = av.y;
      As[ac + 2][ar] = av.z; As[ac + 3][ar] = av.w;
    } else {
      #pragma unroll
      for (int q = 0; q < 4; ++q) {
        int k = k0 + ac + q;
        As[ac + q][ar] = (k < K) ? Arow[k] : 0.f;
      }
    }
    {
      int kk = k0 + br, n = n0 + bc;
      if (kk < K && n + 3 < N) {
        float4 bv = *(const float4*)(WT + (size_t)kk * N + n);
        Bs[br][bc + 0] = bv.x; Bs[br][bc + 1] = bv.y;
        Bs[br][bc + 2] = bv.z; Bs[br][bc + 3] = bv.w;
      } else {
        #pragma unroll
        for (int q = 0; q < 4; ++q) {
          int n2 = n + q;
          Bs[br][bc + q] = (kk < K && n2 < N) ? WT[(size_t)kk * N + n2] : 0.f;
        }
      }
    }
    __syncthreads();
    #pragma unroll
    for (int kk = 0; kk < 16; ++kk) {
      float av[4], bv[4];
      #pragma unroll
      for (int i = 0; i < 4; ++i) av[i] = As[kk][ty * 4 + i];
      #pragma unroll
      for (int j = 0; j < 4; ++j) bv[j] = Bs[kk][tx * 4 + j];
      #pragma unroll
      for (int i = 0; i < 4; ++i)
        #pragma unroll
        for (int j = 0; j < 4; ++j) acc[i][j] += av[i] * bv[j];
    }
    __syncthreads();
  }
  #pragma unroll
  for (int i = 0; i < 4; ++i) {
    int m = m0 + ty * 4 + i;
    int b = m >> 6, s = m & 63;
    int t = rev ? 63 - s : s;
    int mt = b >> 4, bl = b & 15;
    int hi2 = bl >> 2, r2 = bl & 3;
    #pragma unroll
    for (int j = 0; j < 4; ++j) {
      int n = n0 + tx * 4 + j;
      if (n < N) {
        float v = acc[i][j] + bias[n];
        int g = n / 300, u = n - g * 300;
        int jb = u >> 5, ul = u & 31;
        int nh = ul >> 4, lo2 = ul & 15;
        size_t off = ((((size_t)(rec * 64 + t) * 10 + jb) * 4 + g) * 2 + nh) * 512
                     + mt * 256 + (hi2 * 16 + lo2) * 4 + r2;
        XG2[off] = (f16)v;
      }
    }
  }
}

// ---------------- distributed MFMA LSTM, fence-free coherent-atomic sync ----
// 40 blocks = 4 rec x 10 u-tiles; 8 waves = (g, nh). Weight frags in regs.
// h exchanged via RELAXED agent-scope atomics (bypass L2, coherent at L3):
// no threadfence / L2 wb-inv anywhere. Counter per rec, 128B padded.
__global__ __launch_bounds__(512, 1) void k_lstm4(
    const f16* __restrict__ Wh, const f16* __restrict__ XG2,
    unsigned int* __restrict__ Hbuf, float* __restrict__ O,
    unsigned int* __restrict__ cnt) {
  int bid = blockIdx.x;
  int rec = bid / 10, jb = bid - rec * 10;
  int tid = threadIdx.x;
  int w = tid >> 6, l = tid & 63, lo = l & 15, hi = l >> 4;
  int g = w & 3, nh = w >> 2;

  __shared__ f16 Hs[32][328];
  __shared__ float zs[4][32][33];

  const f16* Wd = Wh + (size_t)(rec & 1) * 409600;
  int u_t = jb * 32 + nh * 16 + lo;
  f16x8 Bf[10];
  #pragma unroll
  for (int kt = 0; kt < 10; ++kt)
    Bf[kt] = *(const f16x8*)(Wd + ((size_t)g * 320 + u_t) * 320 + kt * 32 + hi * 8);

  int cb = tid >> 4, cup = tid & 15;
  int u0c = jb * 32 + cup * 2;
  float c0 = 0.f, c1 = 0.f;
  unsigned int* cp = cnt + rec * 32;          // 128B-padded counters
  const f16* xgbase = XG2 + ((size_t)(rec * 64) * 10 + jb) * 4096
                      + ((size_t)(g * 2 + nh)) * 512 + l * 4;

  for (int t = 0; t < 64; ++t) {
    if (t > 0) {
      if (tid == 0) {
        while (__hip_atomic_load(cp, __ATOMIC_RELAXED, __HIP_MEMORY_SCOPE_AGENT)
               < 10u * (unsigned)t)
          __builtin_amdgcn_s_sleep(1);
      }
      __syncthreads();
      asm volatile("" ::: "memory");
    }
    // stage h_t (20 KB): coherent u64 loads (bypass L2) -> LDS
    {
      unsigned long long* Hg = (unsigned long long*)
          (Hbuf + ((size_t)(t & 1) * 4 + rec) * 5120);
      #pragma unroll
      for (int q = 0; q < 5; ++q) {
        int idx = q * 512 + tid;             // 0..2559 u64
        unsigned long long v = __hip_atomic_load(Hg + idx, __ATOMIC_RELAXED,
                                                 __HIP_MEMORY_SCOPE_AGENT);
        int b = idx / 80, rm = idx - b * 80;
        *(unsigned long long*)(&Hs[b][rm * 4]) = v;
      }
    }
    __syncthreads();

    // z = Whh_g . h  (2 mt x 10 kt MFMAs per wave) + xg
    const f16* xt = xgbase + (size_t)t * 40960;
    f32x4 acc[2] = {};
    #pragma unroll
    for (int kt = 0; kt < 10; ++kt) {
      #pragma unroll
      for (int mt = 0; mt < 2; ++mt) {
        f16x8 Af = *(const f16x8*)(&Hs[mt * 16 + lo][kt * 32 + hi * 8]);
        acc[mt] = __builtin_amdgcn_mfma_f32_16x16x32_f16(Af, Bf[kt], acc[mt], 0, 0, 0);
      }
    }
    #pragma unroll
    for (int mt = 0; mt < 2; ++mt) {
      f16x4 xv = *(const f16x4*)(xt + mt * 256);
      #pragma unroll
      for (int r = 0; r < 4; ++r)
        zs[g][mt * 16 + hi * 4 + r][nh * 16 + lo] = acc[mt][r] + (float)xv[r];
    }
    __syncthreads();

    // gates: thread owns (b=cb, u = u0c, u0c+1)
    int tt = (rec & 1) ? 63 - t : t;
    float h0n, h1n;
    {
      int uu = cup * 2;
      float zi = zs[0][cb][uu], zf = zs[1][cb][uu];
      float zg = zs[2][cb][uu], zo = zs[3][cb][uu];
      float si = 1.f / (1.f + expf(-zi));
      float sf = 1.f / (1.f + expf(-zf));
      float so = 1.f / (1.f + expf(-zo));
      float cn = sf * c0 + si * tanhf(zg);
      h0n = so * tanhf(cn);
      c0 = cn;
      zi = zs[0][cb][uu + 1]; zf = zs[1][cb][uu + 1];
      zg = zs[2][cb][uu + 1]; zo = zs[3][cb][uu + 1];
      si = 1.f / (1.f + expf(-zi));
      sf = 1.f / (1.f + expf(-zf));
      so = 1.f / (1.f + expf(-zo));
      cn = sf * c1 + si * tanhf(zg);
      h1n = so * tanhf(cn);
      c1 = cn;
    }
    if (u0c >= 300) { h0n = 0.f; h1n = 0.f; }
    union { f16x2 h; unsigned int u; } pk;
    pk.h[0] = (f16)h0n; pk.h[1] = (f16)h1n;
    unsigned int* Hw = Hbuf + ((size_t)((t + 1) & 1) * 4 + rec) * 5120;
    __hip_atomic_store(Hw + cb * 160 + jb * 16 + cup, pk.u, __ATOMIC_RELAXED,
                       __HIP_MEMORY_SCOPE_AGENT);
    if (O && u0c < 300) {
      float2 ov; ov.x = h0n; ov.y = h1n;
      *(float2*)(O + ((size_t)rec * 2048 + cb * 64 + tt) * 300 + u0c) = ov;
    }
    asm volatile("s_waitcnt vmcnt(0)" ::: "memory");   // h stores acked at L3
    __syncthreads();
    if (tid == 0)
      __hip_atomic_fetch_add(cp, 1u, __ATOMIC_RELAXED, __HIP_MEMORY_SCOPE_AGENT);
  }
}

// ---------------- plain L2 norms of the 4 ctx outputs ----------------
__global__ __launch_bounds__(256) void k_norms(const float* __restrict__ O,
        float* __restrict__ NRM) {
  int idx = blockIdx.x * 4 + (threadIdx.x >> 6);
  int lane = threadIdx.x & 63;
  const float* p = O + (size_t)idx * 300;
  float s = 0.f;
  for (int h = lane; h < 300; h += 64) { float v = p[h]; s += v * v; }
  #pragma unroll
  for (int off = 32; off; off >>= 1) s += __shfl_xor(s, off);
  if (lane == 0) NRM[idx] = sqrtf(s);
}

// ---------------- cosine matrices ----------------
__global__ __launch_bounds__(256) void k_cos(const float* __restrict__ O,
        const float* __restrict__ NRM, float* __restrict__ COS) {
  int b = blockIdx.x, d = blockIdx.y;
  int r1 = d, r2 = 2 + d;
  const float* A = O + ((size_t)r1 * M_ + b * S_) * 300;
  const float* Bm = O + ((size_t)r2 * M_ + b * S_) * 300;
  __shared__ float As[64][33], Bs[64][33];
  int tid = threadIdx.x;
  int tx = tid & 15, ty = tid >> 4;
  int lr = tid >> 2, lc = (tid & 3) * 8;
  float acc[4][4] = {};
  for (int k0 = 0; k0 < 300; k0 += 32) {
    if (k0 + 32 <= 300) {
      float4 a0 = *(const float4*)(A + (size_t)lr * 300 + k0 + lc);
      float4 a1 = *(const float4*)(A + (size_t)lr * 300 + k0 + lc + 4);
      As[lr][lc + 0] = a0.x; As[lr][lc + 1] = a0.y; As[lr][lc + 2] = a0.z; As[lr][lc + 3] = a0.w;
      As[lr][lc + 4] = a1.x; As[lr][lc + 5] = a1.y; As[lr][lc + 6] = a1.z; As[lr][lc + 7] = a1.w;
      float4 b0 = *(const float4*)(Bm + (size_t)lr * 300 + k0 + lc);
      float4 b1 = *(const float4*)(Bm + (size_t)lr * 300 + k0 + lc + 4);
      Bs[lr][lc + 0] = b0.x; Bs[lr][lc + 1] = b0.y; Bs[lr][lc + 2] = b0.z; Bs[lr][lc + 3] = b0.w;
      Bs[lr][lc + 4] = b1.x; Bs[lr][lc + 5] = b1.y; Bs[lr][lc + 6] = b1.z; Bs[lr][lc + 7] = b1.w;
    } else {
      #pragma unroll
      for (int q = 0; q < 8; ++q) {
        int k = k0 + lc + q;
        As[lr][lc + q] = (k < 300) ? A[(size_t)lr * 300 + k] : 0.f;
        Bs[lr][lc + q] = (k < 300) ? Bm[(size_t)lr * 300 + k] : 0.f;
      }
    }
    __syncthreads();
    #pragma unroll
    for (int kk = 0; kk < 32; ++kk) {
      float av[4], bv[4];
      #pragma unroll
      for (int i = 0; i < 4; ++i) av[i] = As[ty * 4 + i][kk];
      #pragma unroll
      for (int j = 0; j < 4; ++j) bv[j] = Bs[tx * 4 + j][kk];
      #pragma unroll
      for (int i = 0; i < 4; ++i)
        #pragma unroll
        for (int j = 0; j < 4; ++j) acc[i][j] += av[i] * bv[j];
    }
    __syncthreads();
  }
  float n1[4], n2[4];
  #pragma unroll
  for (int i = 0; i < 4; ++i) {
    n1[i] = NRM[(size_t)r1 * M_ + b * S_ + ty * 4 + i];
    n2[i] = NRM[(size_t)r2 * M_ + b * S_ + tx * 4 + i];
  }
  float* outp = COS + ((size_t)d * 32 + b) * 4096;
  #pragma unroll
  for (int i = 0; i < 4; ++i)
    #pragma unroll
    for (int j = 0; j < 4; ++j)
      outp[(ty * 4 + i) * 64 + tx * 4 + j] = acc[i][j] / (n1[i] * n2[j]);
}

// ---------------- cos row/col sums ----------------
__global__ __launch_bounds__(64) void k_csum(const float* __restrict__ COS,
        float* __restrict__ RS, float* __restrict__ CS) {
  int b = blockIdx.x, d = blockIdx.y, t = threadIdx.x;
  const float* base = COS + ((size_t)d * 32 + b) * 4096;
  float rs = 0.f, cs = 0.f;
  for (int k = 0; k < 64; ++k) { rs += base[t * 64 + k]; cs += base[k * 64 + t]; }
  RS[(d * 32 + b) * 64 + t] = rs;
  CS[(d * 32 + b) * 64 + t] = cs;
}

// ---- pairwise match + fused max over i and j (PAIR never materialized) ----
__global__ __launch_bounds__(256) void k_pairfused(const float* __restrict__ O,
        const float* __restrict__ NRM, const float* __restrict__ Wf,
        const float* __restrict__ Wb, float* __restrict__ V1, float* __restrict__ V2) {
  int b = blockIdx.x, lidx = blockIdx.y, d = blockIdx.z;
  int r1 = d;
  const float* A = O + ((size_t)r1 * M_ + b * S_) * 300;
  const float* Bm = O + ((size_t)3 * M_ + b * S_) * 300;
  const float* Wl = (d ? Wb : Wf) + (size_t)lidx * 300;
  __shared__ float As[64][33], Bs[64][33];
  int tid = threadIdx.x;
  int tx = tid & 15, ty = tid >> 4;
  int lr = tid >> 2, lc = (tid & 3) * 8;
  float acc[4][4] = {};
  for (int k0 = 0; k0 < 300; k0 += 32) {
    if (k0 + 32 <= 300) {
      float4 a0 = *(const float4*)(A + (size_t)lr * 300 + k0 + lc);
      float4 a1 = *(const float4*)(A + (size_t)lr * 300 + k0 + lc + 4);
      float4 w0 = *(const float4*)(Wl + k0 + lc);
      float4 w1 = *(const float4*)(Wl + k0 + lc + 4);
      As[lr][lc + 0] = a0.x * w0.x * w0.x; As[lr][lc + 1] = a0.y * w0.y * w0.y;
      As[lr][lc + 2] = a0.z * w0.z * w0.z; As[lr][lc + 3] = a0.w * w0.w * w0.w;
      As[lr][lc + 4] = a1.x * w1.x * w1.x; As[lr][lc + 5] = a1.y * w1.y * w1.y;
      As[lr][lc + 6] = a1.z * w1.z * w1.z; As[lr][lc + 7] = a1.w * w1.w * w1.w;
      float4 b0 = *(const float4*)(Bm + (size_t)lr * 300 + k0 + lc);
      float4 b1 = *(const float4*)(Bm + (size_t)lr * 300 + k0 + lc + 4);
      Bs[lr][lc + 0] = b0.x; Bs[lr][lc + 1] = b0.y; Bs[lr][lc + 2] = b0.z; Bs[lr][lc + 3] = b0.w;
      Bs[lr][lc + 4] = b1.x; Bs[lr][lc + 5] = b1.y; Bs[lr][lc + 6] = b1.z; Bs[lr][lc + 7] = b1.w;
    } else {
      #pragma unroll
      for (int q = 0; q < 8; ++q) {
        int k = k0 + lc + q;
        float w = (k < 300) ? Wl[k] : 0.f;
        As[lr][lc + q] = (k < 300) ? A[(size_t)lr * 300 + k] * w * w : 0.f;
        Bs[lr][lc + q] = (k < 300) ? Bm[(size_t)lr * 300 + k] : 0.f;
      }
    }
    __syncthreads();
    #pragma unroll
    for (int kk = 0; kk < 32; ++kk) {
      float av[4], bv[4];
      #pragma unroll
      for (int i = 0; i < 4; ++i) av[i] = As[ty * 4 + i][kk];
      #pragma unroll
      for (int j = 0; j < 4; ++j) bv[j] = Bs[tx * 4 + j][kk];
      #pragma unroll
      for (int i = 0; i < 4; ++i)
        #pragma unroll
        for (int j = 0; j < 4; ++j) acc[i][j] += av[i] * bv[j];
    }
    __syncthreads();
  }
  float n1[4], n2[4];
  #pragma unroll
  for (int i = 0; i < 4; ++i) {
    n1[i] = NRM[(size_t)r1 * M_ + b * S_ + ty * 4 + i];
    n2[i] = NRM[(size_t)3 * M_ + b * S_ + tx * 4 + i];
  }
  int offv = (d ? 100 : 20) + lidx;
  float mj[4], mi[4];
  #pragma unroll
  for (int q = 0; q < 4; ++q) { mj[q] = -INFINITY; mi[q] = -INFINITY; }
  #pragma unroll
  for (int i = 0; i < 4; ++i)
    #pragma unroll
    for (int j = 0; j < 4; ++j) {
      float v = acc[i][j] / (n1[i] * n2[j]);
      mj[i] = fmaxf(mj[i], v);
      mi[j] = fmaxf(mi[j], v);
    }
  #pragma unroll
  for (int off = 1; off < 16; off <<= 1)
    #pragma unroll
    for (int i = 0; i < 4; ++i) mj[i] = fmaxf(mj[i], __shfl_xor(mj[i], off));
  if (tx == 0)
    #pragma unroll
    for (int i = 0; i < 4; ++i)
      V1[((size_t)b * S_ + ty * 4 + i) * 160 + offv] = mj[i];
  float* red = &As[0][0];
  __syncthreads();
  #pragma unroll
  for (int j = 0; j < 4; ++j) red[(tx * 4 + j) * 16 + ty] = mi[j];
  __syncthreads();
  if (tid < 64) {
    float m = red[tid * 16];
    #pragma unroll
    for (int yy = 1; yy < 16; ++yy) m = fmaxf(m, red[tid * 16 + yy]);
    V2[((size_t)b * S_ + tid) * 160 + offv] = m;
  }
}

// ---------------- mean/max attention vectors MM[v][b][r][h] ----------------
__global__ __launch_bounds__(128) void k_meanmax(const float* __restrict__ O,
        const float* __restrict__ COS, const float* __restrict__ RS,
        const float* __restrict__ CS, float* __restrict__ MM) {
  int b = blockIdx.x, rg = blockIdx.y, v = blockIdx.z;
  int isMax = v >> 2, vv = v & 3;
  int d = vv & 1, s2side = vv >> 1;
  int srcrec = s2side ? 0 : 2;
  const float* SRC = O + ((size_t)srcrec * M_ + b * S_) * 300;
  const float* Cb = COS + ((size_t)d * 32 + b) * 4096;
  int tid = threadIdx.x;
  int h0 = tid, h1 = tid + 128, h2 = tid + 256;
  bool has2 = (h2 < 300);
  float init = isMax ? -INFINITY : 0.f;
  float acc[8][3];
  #pragma unroll
  for (int rr = 0; rr < 8; ++rr) { acc[rr][0] = init; acc[rr][1] = init; acc[rr][2] = init; }
  int r0 = rg * 8;
  for (int inner = 0; inner < 64; ++inner) {
    float s0 = SRC[(size_t)inner * 300 + h0];
    float s1 = SRC[(size_t)inner * 300 + h1];
    float s2v = has2 ? SRC[(size_t)inner * 300 + h2] : 0.f;
    #pragma unroll
    for (int rr = 0; rr < 8; ++rr) {
      int r = r0 + rr;
      float cv = s2side ? Cb[inner * 64 + r] : Cb[r * 64 + inner];
      if (isMax) {
        acc[rr][0] = fmaxf(acc[rr][0], cv * s0);
        acc[rr][1] = fmaxf(acc[rr][1], cv * s1);
        acc[rr][2] = fmaxf(acc[rr][2], cv * s2v);
      } else {
        acc[rr][0] += cv * s0; acc[rr][1] += cv * s1; acc[rr][2] += cv * s2v;
      }
    }
  }
  float* outp = MM + (size_t)v * 614400;
  for (int rr = 0; rr < 8; ++rr) {
    int r = r0 + rr;
    size_t o = ((size_t)b * S_ + r) * 300;
    if (isMax) {
      outp[o + h0] = acc[rr][0];
      outp[o + h1] = acc[rr][1];
      if (has2) outp[o + h2] = acc[rr][2];
    } else {
      float den = s2side ? CS[(d * 32 + b) * 64 + r] : RS[(d * 32 + b) * 64 + r];
      outp[o + h0] = acc[rr][0] / den;
      outp[o + h1] = acc[rr][1] / den;
      if (has2) outp[o + h2] = acc[rr][2] / den;
    }
  }
}

// ---------------- generic full-match (12 variants) ----------------
__global__ __launch_bounds__(256) void k_fullmatch(const float* __restrict__ O,
        const float* __restrict__ MM, const float* __restrict__ Wff,
        const float* __restrict__ Wfb, const float* __restrict__ Wat,
        const float* __restrict__ Wmx, float* __restrict__ V1, float* __restrict__ V2) {
  int item = blockIdx.x * 4 + (threadIdx.x >> 6);
  int lane = threadIdx.x & 63;
  int b = item >> 6, s = item & 63;
  int var = blockIdx.y;
  size_t ms = (size_t)b * S_ + s;
  const float* s1f = O;
  const float* s1b = O + (size_t)M_ * 300;
  const float* s2f = O + (size_t)2 * M_ * 300;
  const float* s2b = O + (size_t)3 * M_ * 300;
  const float *v1p, *v2p, *W;
  float* outp;
  switch (var) {
    case 0:  v1p = s1f + ms * 300; v2p = s2f + ((size_t)b * S_ + 63) * 300; W = Wff; outp = V1 + ms * 160 + 0;   break;
    case 1:  v1p = s1f + ms * 300; v2p = MM + (size_t)0 * 614400 + ms * 300; W = Wat; outp = V1 + ms * 160 + 40; break;
    case 2:  v1p = s1f + ms * 300; v2p = MM + (size_t)4 * 614400 + ms * 300; W = Wmx; outp = V1 + ms * 160 + 60; break;
    case 3:  v1p = s1b + ms * 300; v2p = s2b + ((size_t)b * S_ + 0) * 300;  W = Wfb; outp = V1 + ms * 160 + 80;  break;
    case 4:  v1p = s1b + ms * 300; v2p = MM + (size_t)1 * 614400 + ms * 300; W = Wat; outp = V1 + ms * 160 + 120; break;
    case 5:  v1p = s1b + ms * 300; v2p = MM + (size_t)5 * 614400 + ms * 300; W = Wmx; outp = V1 + ms * 160 + 140; break;
    case 6:  v1p = s2f + ms * 300; v2p = s1f + ((size_t)b * S_ + 63) * 300; W = Wff; outp = V2 + ms * 160 + 0;   break;
    case 7:  v1p = s2f + ms * 300; v2p = MM + (size_t)2 * 614400 + ms * 300; W = Wat; outp = V2 + ms * 160 + 40; break;
    case 8:  v1p = s2f + ms * 300; v2p = MM + (size_t)6 * 614400 + ms * 300; W = Wmx; outp = V2 + ms * 160 + 60; break;
    case 9:  v1p = s2b + ms * 300; v2p = s1b + ((size_t)b * S_ + 0) * 300;  W = Wfb; outp = V2 + ms * 160 + 80;  break;
    case 10: v1p = s2b + ms * 300; v2p = MM + (size_t)3 * 614400 + ms * 300; W = Wat; outp = V2 + ms * 160 + 120; break;
    default: v1p = s2b + ms * 300; v2p = MM + (size_t)7 * 614400 + ms * 300; W = Wmx; outp = V2 + ms * 160 + 140; break;
  }
  float av[5], bv[5], ab[5], a2[5], b2[5];
  #pragma unroll
  for (int q = 0; q < 5; ++q) {
    int h = lane + 64 * q;
    bool in = (h < 300);
    av[q] = in ? v1p[h] : 0.f;
    bv[q] = in ? v2p[h] : 0.f;
    ab[q] = av[q] * bv[q];
    a2[q] = av[q] * av[q];
    b2[q] = bv[q] * bv[q];
  }
  for (int lq = 0; lq < 20; ++lq) {
    float sn = 0.f, sa = 0.f, sb = 0.f;
    #pragma unroll
    for (int q = 0; q < 5; ++q) {
      int h = lane + 64 * q;
      if (h < 300) {
        float w = W[(size_t)lq * 300 + h];
        float w2 = w * w;
        sn += w2 * ab[q]; sa += w2 * a2[q]; sb += w2 * b2[q];
      }
    }
    #pragma unroll
    for (int off = 32; off; off >>= 1) {
      sn += __shfl_xor(sn, off);
      sa += __shfl_xor(sa, off);
      sb += __shfl_xor(sb, off);
    }
    if (lane == 0) {
      float n1 = fmaxf(sqrtf(sa), EPSF);
      float n2 = fmaxf(sqrtf(sb), EPSF);
      outp[lq] = sn / (n1 * n2);
    }
  }
}

// ---------------- final MLP + log_softmax ----------------
__global__ __launch_bounds__(256) void k_mlp(const f16* __restrict__ H16,
        const float* __restrict__ W1T, const float* __restrict__ b1,
        const float* __restrict__ W2, const float* __restrict__ b2,
        float* __restrict__ out) {
  int b = blockIdx.x, tid = threadIdx.x;
  __shared__ float mvs[1200];
  __shared__ float xs[600];
  __shared__ float red[2][4];
  for (int i = tid; i < 1200; i += 256) {
    int r = i / 300, h = i - r * 300;
    mvs[i] = (float)H16[((size_t)r * 32 + b) * 320 + h];
  }
  __syncthreads();
  for (int o = tid; o < 600; o += 256) {
    float dot = b1[o];
    for (int k = 0; k < 1200; ++k) dot += mvs[k] * W1T[(size_t)k * 600 + o];
    xs[o] = tanhf(dot);
  }
  __syncthreads();
  float p0 = 0.f, p1 = 0.f;
  for (int k = tid; k < 600; k += 256) {
    float xv = xs[k];
    p0 += xv * W2[k];
    p1 += xv * W2[600 + k];
  }
  #pragma unroll
  for (int off = 32; off; off >>= 1) { p0 += __shfl_xor(p0, off); p1 += __shfl_xor(p1, off); }
  int w = tid >> 6;
  if ((tid & 63) == 0) { red[0][w] = p0; red[1][w] = p1; }
  __syncthreads();
  if (tid == 0) {
    float l0 = red[0][0] + red[0][1] + red[0][2] + red[0][3] + b2[0];
    float l1 = red[1][0] + red[1][1] + red[1][2] + red[1][3] + b2[1];
    float m = fmaxf(l0, l1);
    float lse = m + logf(expf(l0 - m) + expf(l1 - m));
    out[b * 2 + 0] = l0 - lse;
    out[b * 2 + 1] = l1 - lse;
  }
}

extern "C" void kernel_launch(void* const* d_in, const int* in_sizes, int n_in,
                              void* d_out, int out_size, void* d_ws, size_t ws_size,
                              hipStream_t stream) {
  (void)in_sizes; (void)out_size;
  if (n_in < 25) return;
  const float* emb    = (const float*)d_in[0];
  const float* cWihF  = (const float*)d_in[1];
  const float* cWhhF  = (const float*)d_in[2];
  const float* cbF    = (const float*)d_in[3];
  const float* cWihB  = (const float*)d_in[4];
  const float* cWhhB  = (const float*)d_in[5];
  const float* cbB    = (const float*)d_in[6];
  const float* aWihF  = (const float*)d_in[7];
  const float* aWhhF  = (const float*)d_in[8];
  const float* abF    = (const float*)d_in[9];
  const float* aWihB  = (const float*)d_in[10];
  const float* aWhhB  = (const float*)d_in[11];
  const float* abB    = (const float*)d_in[12];
  const float* WfullF = (const float*)d_in[13];
  const float* WfullB = (const float*)d_in[14];
  const float* WmaxpF = (const float*)d_in[15];
  const float* WmaxpB = (const float*)d_in[16];
  const float* WattnF = (const float*)d_in[17];
  const float* WmaxaF = (const float*)d_in[18];
  const float* pW1    = (const float*)d_in[19];
  const float* pb1    = (const float*)d_in[20];
  const float* pW2    = (const float*)d_in[21];
  const float* pb2    = (const float*)d_in[22];
  const int*   sa     = (const int*)d_in[23];
  const int*   sb     = (const int*)d_in[24];
  float* out = (float*)d_out;
  float* ws = (float*)d_ws;

  // ---- workspace layout (float offsets) ----
  if (ws_size < (size_t)11318720 * 4) return;
  float* WT_cihF = ws + 0;          //  360000
  float* WT_cihB = ws + 360000;     //  360000
  float* WT_aihF = ws + 720000;     //  192000
  float* WT_aihB = ws + 912000;     //  192000
  float* W1T     = ws + 1104000;    //  720000
  f16*   Wh16    = (f16*)(ws + 1824000);   // 4*409600 f16 = 819200 fl
  unsigned int* Hbuf = (unsigned int*)(ws + 2643200);  // 2x4x5120 u32 = 40960 fl
  unsigned int* cnt  = (unsigned int*)(ws + 2684160);  // 4 x 32 u32 = 128 fl
  float* NRM  = ws + 2684288;       //    8192
  float* COS  = ws + 2692480;       //  262144
  float* RS   = ws + 2954624;       //    4096
  float* CS   = ws + 2958720;       //    4096
  float* V1   = ws + 2962816;       //  327680
  float* V2   = ws + 3290496;       //  327680
  f16*   XG2  = (f16*)(ws + 3618176);      // 10485760 f16 = 5242880 fl
  float* MM   = ws + 3618176;       //  alias (4915200 <= 5242880)
  float* O    = ws + 8861056;       //  2457600

  f16* WhCtx = Wh16;
  f16* WhAgg = Wh16 + (size_t)2 * 409600;

  // ---- weight prep ----
  k_transpose<<<dim3(10, 38), 256, 0, stream>>>(cWihF, WT_cihF, 1200, 300);
  k_transpose<<<dim3(10, 38), 256, 0, stream>>>(cWihB, WT_cihB, 1200, 300);
  k_transpose<<<dim3(5, 38), 256, 0, stream>>>(aWihF, WT_aihF, 1200, 160);
  k_transpose<<<dim3(5, 38), 256, 0, stream>>>(aWihB, WT_aihB, 1200, 160);
  k_transpose<<<dim3(38, 19), 256, 0, stream>>>(pW1, W1T, 600, 1200);
  k_wh16<<<1600, 256, 0, stream>>>(cWhhF, WhCtx);
  k_wh16<<<1600, 256, 0, stream>>>(cWhhB, WhCtx + 409600);
  k_wh16<<<1600, 256, 0, stream>>>(aWhhF, WhAgg);
  k_wh16<<<1600, 256, 0, stream>>>(aWhhB, WhAgg + 409600);

  // ---- context BiLSTM ----
  k_proj<<<dim3(32, 19), 256, 0, stream>>>(emb, sa, WT_cihF, cbF, XG2, 1200, 300, 300, 0, 0);
  k_proj<<<dim3(32, 19), 256, 0, stream>>>(emb, sa, WT_cihB, cbB, XG2, 1200, 300, 300, 1, 1);
  k_proj<<<dim3(32, 19), 256, 0, stream>>>(emb, sb, WT_cihF, cbF, XG2, 1200, 300, 300, 2, 0);
  k_proj<<<dim3(32, 19), 256, 0, stream>>>(emb, sb, WT_cihB, cbB, XG2, 1200, 300, 300, 3, 1);
  hipMemsetAsync(Hbuf, 0, 81920, stream);              // parity-0 h = 0
  hipMemsetAsync(cnt, 0, 512, stream);
  k_lstm4<<<40, 512, 0, stream>>>(WhCtx, XG2, Hbuf, O, cnt);

  // ---- matching ----
  k_norms<<<2048, 256, 0, stream>>>(O, NRM);
  k_cos<<<dim3(32, 2), 256, 0, stream>>>(O, NRM, COS);
  k_csum<<<dim3(32, 2), 64, 0, stream>>>(COS, RS, CS);
  k_pairfused<<<dim3(32, 20, 2), 256, 0, stream>>>(O, NRM, WmaxpF, WmaxpB, V1, V2);
  k_meanmax<<<dim3(32, 8, 8), 128, 0, stream>>>(O, COS, RS, CS, MM);
  k_fullmatch<<<dim3(512, 12), 256, 0, stream>>>(O, MM, WfullF, WfullB, WattnF, WmaxaF, V1, V2);

  // ---- aggregation BiLSTM ----
  k_proj<<<dim3(32, 19), 256, 0, stream>>>(V1, nullptr, WT_aihF, abF, XG2, 1200, 160, 160, 0, 0);
  k_proj<<<dim3(32, 19), 256, 0, stream>>>(V1, nullptr, WT_aihB, abB, XG2, 1200, 160, 160, 1, 1);
  k_proj<<<dim3(32, 19), 256, 0, stream>>>(V2, nullptr, WT_aihF, abF, XG2, 1200, 160, 160, 2, 0);
  k_proj<<<dim3(32, 19), 256, 0, stream>>>(V2, nullptr, WT_aihB, abB, XG2, 1200, 160, 160, 3, 1);
  hipMemsetAsync(Hbuf, 0, 81920, stream);
  hipMemsetAsync(cnt, 0, 512, stream);
  k_lstm4<<<40, 512, 0, stream>>>(WhAgg, XG2, Hbuf, nullptr, cnt);

  // ---- prediction head ----
  k_mlp<<<32, 256, 0, stream>>>((const f16*)Hbuf, W1T, pb1, pW2, pb2, out);
}

// Round 7
// 966.042 us; speedup vs baseline: 4.4535x; 1.3326x over previous
//
#include <hip/hip_runtime.h>
#include <math.h>

#define B_ 32
#define S_ 64
#define H_ 300
#define M_ 2048          // B*S
#define EPSF 1e-8f

typedef _Float16 f16;
typedef _Float16 f16x2 __attribute__((ext_vector_type(2)));
typedef _Float16 f16x4 __attribute__((ext_vector_type(4)));
typedef _Float16 f16x8 __attribute__((ext_vector_type(8)));
typedef float f32x4 __attribute__((ext_vector_type(4)));

// ---------------- transpose (R x C) -> (C x R) ----------------
__global__ __launch_bounds__(256) void k_transpose(const float* __restrict__ src,
        float* __restrict__ dst, int R, int C) {
  __shared__ float t[32][33];
  int tx = threadIdx.x & 31, ty = threadIdx.x >> 5;
  int c0 = blockIdx.x * 32, r0 = blockIdx.y * 32;
  #pragma unroll
  for (int q = 0; q < 4; ++q) {
    int r = r0 + ty + q * 8, c = c0 + tx;
    t[ty + q * 8][tx] = (r < R && c < C) ? src[(size_t)r * C + c] : 0.f;
  }
  __syncthreads();
  #pragma unroll
  for (int q = 0; q < 4; ++q) {
    int c = c0 + ty + q * 8, r = r0 + tx;
    if (c < C && r < R) dst[(size_t)c * R + r] = t[tx][ty + q * 8];
  }
}

// ---- Whh (1200x300 f32) -> f16 padded [4 g][320 u][320 k] ----
__global__ __launch_bounds__(256) void k_wh16(const float* __restrict__ W,
        f16* __restrict__ D) {
  int idx = blockIdx.x * 256 + threadIdx.x;
  if (idx >= 409600) return;
  int g = idx / 102400, rem = idx - g * 102400;
  int u = rem / 320, k = rem - u * 320;
  float v = (u < 300 && k < 300) ? W[((size_t)g * 300 + u) * 300 + k] : 0.f;
  D[idx] = (f16)v;
}

// ---- Wih F+B (each 1200 x Kreal) -> f16 [2432][Kpad], zero pad ----
__global__ __launch_bounds__(256) void k_wih16(const float* __restrict__ WF,
        const float* __restrict__ WB, f16* __restrict__ D, int Kreal, int Kpad) {
  int idx = blockIdx.x * 256 + threadIdx.x;
  if (idx >= 2432 * Kpad) return;
  int n = idx / Kpad, k = idx - n * Kpad;
  float v = 0.f;
  if (n < 2400 && k < Kreal) {
    int fb = n >= 1200;
    int nn = n - fb * 1200;
    v = (fb ? WB : WF)[(size_t)nn * Kreal + k];
  }
  D[idx] = (f16)v;
}

// ---- W^2 for fullmatch: 4 x (20x300) -> f16 [4][32][320] ----
__global__ __launch_bounds__(256) void k_wsq16(const float* __restrict__ W0,
        const float* __restrict__ W1, const float* __restrict__ W2,
        const float* __restrict__ W3, f16* __restrict__ D) {
  int idx = blockIdx.x * 256 + threadIdx.x;
  if (idx >= 40960) return;
  int wi = idx / 10240, rem = idx - wi * 10240;
  int r = rem / 320, k = rem - r * 320;
  float v = 0.f;
  if (r < 20 && k < 300) {
    const float* W = wi == 0 ? W0 : wi == 1 ? W1 : wi == 2 ? W2 : W3;
    float w = W[(size_t)r * 300 + k];
    v = w * w;
  }
  D[idx] = (f16)v;
}

// ---------------- MFMA input projection, F+B fused, scatter to XG2 ----------
// A rows in m' = s*32+b order. C tile: m' = m0+w*32+mt*16+hi*4+r, n = n0+nt*16+lo.
// b = mt*16+hi*4+r, s = m0/32+w  ->  XG2 r-slot contiguous => f16x4 stores.
__global__ __launch_bounds__(256) void k_projm(const float* __restrict__ A,
        const int* __restrict__ gather, const f16* __restrict__ B16,
        const float* __restrict__ biasF, const float* __restrict__ biasB,
        f16* __restrict__ XG2, int recbase, int Kreal, int Kpad, int lda) {
  __shared__ f16 As[128][40];
  __shared__ f16 Bs[128][40];
  int tid = threadIdx.x;
  int m0 = blockIdx.x * 128, n0 = blockIdx.y * 128;
  int w = tid >> 6, l = tid & 63, lo = l & 15, hi = l >> 4;
  int srow = tid >> 1, sk = (tid & 1) * 16;
  int sA_s = (m0 + srow) >> 5, sA_b = (m0 + srow) & 31;
  int itemA = sA_b * 64 + sA_s;
  const float* Arow = gather ? (A + (size_t)gather[itemA] * lda)
                             : (A + (size_t)itemA * lda);
  const f16* Brow = B16 + (size_t)(n0 + srow) * Kpad;
  f32x4 acc[2][8] = {};
  int nkt = Kpad >> 5;
  for (int kt = 0; kt < nkt; ++kt) {
    int k0 = kt * 32;
    #pragma unroll
    for (int q = 0; q < 16; q += 4) {
      int k = k0 + sk + q;
      if (k + 4 <= Kreal) {
        float4 v = *(const float4*)(Arow + k);
        As[srow][sk + q + 0] = (f16)v.x; As[srow][sk + q + 1] = (f16)v.y;
        As[srow][sk + q + 2] = (f16)v.z; As[srow][sk + q + 3] = (f16)v.w;
      } else {
        #pragma unroll
        for (int j = 0; j < 4; ++j)
          As[srow][sk + q + j] = (f16)((k + j < Kreal) ? Arow[k + j] : 0.f);
      }
    }
    *(f16x8*)(&Bs[srow][sk]) = *(const f16x8*)(Brow + k0 + sk);
    *(f16x8*)(&Bs[srow][sk + 8]) = *(const f16x8*)(Brow + k0 + sk + 8);
    __syncthreads();
    f16x8 Bf[8];
    #pragma unroll
    for (int nt = 0; nt < 8; ++nt)
      Bf[nt] = *(const f16x8*)(&Bs[nt * 16 + lo][hi * 8]);
    #pragma unroll
    for (int mt = 0; mt < 2; ++mt) {
      f16x8 Af = *(const f16x8*)(&As[w * 32 + mt * 16 + lo][hi * 8]);
      #pragma unroll
      for (int nt = 0; nt < 8; ++nt)
        acc[mt][nt] = __builtin_amdgcn_mfma_f32_16x16x32_f16(Af, Bf[nt], acc[mt][nt], 0, 0, 0);
    }
    __syncthreads();
  }
  int s = (m0 >> 5) + w;
  #pragma unroll
  for (int nt = 0; nt < 8; ++nt) {
    int n = n0 + nt * 16 + lo;
    if (n >= 2400) continue;
    int fb = n >= 1200;
    int nn = n - fb * 1200;
    int g = nn / 300;
    int u = nn - g * 300;
    int jb = u >> 5, ul = u & 31, nh = ul >> 4, lo2 = ul & 15;
    int rec = recbase + fb;
    int t = fb ? 63 - s : s;
    float bias = fb ? biasB[nn] : biasF[nn];
    size_t tbase = ((((size_t)(rec * 64 + t) * 10 + jb) * 4 + g) * 2 + nh) * 512
                   + (size_t)(hi * 16 + lo2) * 4;
    #pragma unroll
    for (int mt = 0; mt < 2; ++mt) {
      f16x4 hv;
      #pragma unroll
      for (int r = 0; r < 4; ++r) hv[r] = (f16)(acc[mt][nt][r] + bias);
      *(f16x4*)(XG2 + tbase + mt * 256) = hv;
    }
  }
}

// ---------------- distributed MFMA LSTM, per-producer flag sync ----------
__global__ __launch_bounds__(512, 1) void k_lstm5(
    const f16* __restrict__ Wh, const f16* __restrict__ XG2,
    unsigned int* __restrict__ Hbuf, float* __restrict__ O,
    unsigned int* __restrict__ flags) {
  int bid = blockIdx.x;
  int rec = bid / 10, jb = bid - rec * 10;
  int tid = threadIdx.x;
  int w = tid >> 6, l = tid & 63, lo = l & 15, hi = l >> 4;
  int g = w & 3, nh = w >> 2;

  __shared__ f16 Hs[32][328];
  __shared__ float zs[4][32][33];

  const f16* Wd = Wh + (size_t)(rec & 1) * 409600;
  int u_t = jb * 32 + nh * 16 + lo;
  f16x8 Bf[10];
  #pragma unroll
  for (int kt = 0; kt < 10; ++kt)
    Bf[kt] = *(const f16x8*)(Wd + ((size_t)g * 320 + u_t) * 320 + kt * 32 + hi * 8);

  int cb = tid >> 4, cup = tid & 15;
  int u0c = jb * 32 + cup * 2;
  float c0 = 0.f, c1 = 0.f;
  unsigned int* fl = flags + rec * 160;      // 10 flags x 16 u32 pad
  const f16* xgbase = XG2 + ((size_t)(rec * 64) * 10 + jb) * 4096
                      + ((size_t)(g * 2 + nh)) * 512 + l * 4;

  for (int t = 0; t < 64; ++t) {
    // xg prefetch (independent of h) — issued before the poll
    const f16* xt = xgbase + (size_t)t * 40960;
    f16x4 xv[2];
    #pragma unroll
    for (int mt = 0; mt < 2; ++mt) xv[mt] = *(const f16x4*)(xt + mt * 256);

    if (t > 0) {
      if (tid < 10) {
        while (__hip_atomic_load(fl + tid * 16, __ATOMIC_RELAXED,
                                 __HIP_MEMORY_SCOPE_AGENT) < (unsigned)t)
          __builtin_amdgcn_s_sleep(1);
      }
      __syncthreads();
    }
    // stage h_t (20 KB): coherent u64 loads -> LDS
    {
      unsigned long long* Hg = (unsigned long long*)
          (Hbuf + ((size_t)(t & 1) * 4 + rec) * 5120);
      #pragma unroll
      for (int q = 0; q < 5; ++q) {
        int idx = q * 512 + tid;
        unsigned long long v = __hip_atomic_load(Hg + idx, __ATOMIC_RELAXED,
                                                 __HIP_MEMORY_SCOPE_AGENT);
        int b = idx / 80, rm = idx - b * 80;
        *(unsigned long long*)(&Hs[b][rm * 4]) = v;
      }
    }
    __syncthreads();

    f32x4 acc[2] = {};
    #pragma unroll
    for (int kt = 0; kt < 10; ++kt) {
      #pragma unroll
      for (int mt = 0; mt < 2; ++mt) {
        f16x8 Af = *(const f16x8*)(&Hs[mt * 16 + lo][kt * 32 + hi * 8]);
        acc[mt] = __builtin_amdgcn_mfma_f32_16x16x32_f16(Af, Bf[kt], acc[mt], 0, 0, 0);
      }
    }
    #pragma unroll
    for (int mt = 0; mt < 2; ++mt)
      #pragma unroll
      for (int r = 0; r < 4; ++r)
        zs[g][mt * 16 + hi * 4 + r][nh * 16 + lo] = acc[mt][r] + (float)xv[mt][r];
    __syncthreads();

    int tt = (rec & 1) ? 63 - t : t;
    float h0n, h1n;
    {
      int uu = cup * 2;
      float zi = zs[0][cb][uu], zf = zs[1][cb][uu];
      float zg = zs[2][cb][uu], zo = zs[3][cb][uu];
      float si = 1.f / (1.f + expf(-zi));
      float sf = 1.f / (1.f + expf(-zf));
      float so = 1.f / (1.f + expf(-zo));
      float cn = sf * c0 + si * tanhf(zg);
      h0n = so * tanhf(cn);
      c0 = cn;
      zi = zs[0][cb][uu + 1]; zf = zs[1][cb][uu + 1];
      zg = zs[2][cb][uu + 1]; zo = zs[3][cb][uu + 1];
      si = 1.f / (1.f + expf(-zi));
      sf = 1.f / (1.f + expf(-zf));
      so = 1.f / (1.f + expf(-zo));
      cn = sf * c1 + si * tanhf(zg);
      h1n = so * tanhf(cn);
      c1 = cn;
    }
    if (u0c >= 300) { h0n = 0.f; h1n = 0.f; }
    union { f16x2 h; unsigned int u; } pk;
    pk.h[0] = (f16)h0n; pk.h[1] = (f16)h1n;
    unsigned int* Hw = Hbuf + ((size_t)((t + 1) & 1) * 4 + rec) * 5120;
    __hip_atomic_store(Hw + cb * 160 + jb * 16 + cup, pk.u, __ATOMIC_RELAXED,
                       __HIP_MEMORY_SCOPE_AGENT);
    if (O && u0c < 300) {
      float2 ov; ov.x = h0n; ov.y = h1n;
      *(float2*)(O + ((size_t)rec * 2048 + cb * 64 + tt) * 300 + u0c) = ov;
    }
    asm volatile("s_waitcnt vmcnt(0)" ::: "memory");   // h stores acked at L3
    __syncthreads();
    if (tid == 0)
      __hip_atomic_store(fl + jb * 16, (unsigned)(t + 1), __ATOMIC_RELAXED,
                         __HIP_MEMORY_SCOPE_AGENT);
  }
}

// ---------------- plain L2 norms of the 4 ctx outputs ----------------
__global__ __launch_bounds__(256) void k_norms(const float* __restrict__ O,
        float* __restrict__ NRM) {
  int idx = blockIdx.x * 4 + (threadIdx.x >> 6);
  int lane = threadIdx.x & 63;
  const float* p = O + (size_t)idx * 300;
  float s = 0.f;
  for (int h = lane; h < 300; h += 64) { float v = p[h]; s += v * v; }
  #pragma unroll
  for (int off = 32; off; off >>= 1) s += __shfl_xor(s, off);
  if (lane == 0) NRM[idx] = sqrtf(s);
}

// ---------------- cosine matrices ----------------
__global__ __launch_bounds__(256) void k_cos(const float* __restrict__ O,
        const float* __restrict__ NRM, float* __restrict__ COS) {
  int b = blockIdx.x, d = blockIdx.y;
  int r1 = d, r2 = 2 + d;
  const float* A = O + ((size_t)r1 * M_ + b * S_) * 300;
  const float* Bm = O + ((size_t)r2 * M_ + b * S_) * 300;
  __shared__ float As[64][33], Bs[64][33];
  int tid = threadIdx.x;
  int tx = tid & 15, ty = tid >> 4;
  int lr = tid >> 2, lc = (tid & 3) * 8;
  float acc[4][4] = {};
  for (int k0 = 0; k0 < 300; k0 += 32) {
    if (k0 + 32 <= 300) {
      float4 a0 = *(const float4*)(A + (size_t)lr * 300 + k0 + lc);
      float4 a1 = *(const float4*)(A + (size_t)lr * 300 + k0 + lc + 4);
      As[lr][lc + 0] = a0.x; As[lr][lc + 1] = a0.y; As[lr][lc + 2] = a0.z; As[lr][lc + 3] = a0.w;
      As[lr][lc + 4] = a1.x; As[lr][lc + 5] = a1.y; As[lr][lc + 6] = a1.z; As[lr][lc + 7] = a1.w;
      float4 b0 = *(const float4*)(Bm + (size_t)lr * 300 + k0 + lc);
      float4 b1 = *(const float4*)(Bm + (size_t)lr * 300 + k0 + lc + 4);
      Bs[lr][lc + 0] = b0.x; Bs[lr][lc + 1] = b0.y; Bs[lr][lc + 2] = b0.z; Bs[lr][lc + 3] = b0.w;
      Bs[lr][lc + 4] = b1.x; Bs[lr][lc + 5] = b1.y; Bs[lr][lc + 6] = b1.z; Bs[lr][lc + 7] = b1.w;
    } else {
      #pragma unroll
      for (int q = 0; q < 8; ++q) {
        int k = k0 + lc + q;
        As[lr][lc + q] = (k < 300) ? A[(size_t)lr * 300 + k] : 0.f;
        Bs[lr][lc + q] = (k < 300) ? Bm[(size_t)lr * 300 + k] : 0.f;
      }
    }
    __syncthreads();
    #pragma unroll
    for (int kk = 0; kk < 32; ++kk) {
      float av[4], bv[4];
      #pragma unroll
      for (int i = 0; i < 4; ++i) av[i] = As[ty * 4 + i][kk];
      #pragma unroll
      for (int j = 0; j < 4; ++j) bv[j] = Bs[tx * 4 + j][kk];
      #pragma unroll
      for (int i = 0; i < 4; ++i)
        #pragma unroll
        for (int j = 0; j < 4; ++j) acc[i][j] += av[i] * bv[j];
    }
    __syncthreads();
  }
  float n1[4], n2[4];
  #pragma unroll
  for (int i = 0; i < 4; ++i) {
    n1[i] = NRM[(size_t)r1 * M_ + b * S_ + ty * 4 + i];
    n2[i] = NRM[(size_t)r2 * M_ + b * S_ + tx * 4 + i];
  }
  float* outp = COS + ((size_t)d * 32 + b) * 4096;
  #pragma unroll
  for (int i = 0; i < 4; ++i)
    #pragma unroll
    for (int j = 0; j < 4; ++j)
      outp[(ty * 4 + i) * 64 + tx * 4 + j] = acc[i][j] / (n1[i] * n2[j]);
}

// ---------------- cos row/col sums ----------------
__global__ __launch_bounds__(64) void k_csum(const float* __restrict__ COS,
        float* __restrict__ RS, float* __restrict__ CS) {
  int b = blockIdx.x, d = blockIdx.y, t = threadIdx.x;
  const float* base = COS + ((size_t)d * 32 + b) * 4096;
  float rs = 0.f, cs = 0.f;
  for (int k = 0; k < 64; ++k) { rs += base[t * 64 + k]; cs += base[k * 64 + t]; }
  RS[(d * 32 + b) * 64 + t] = rs;
  CS[(d * 32 + b) * 64 + t] = cs;
}

// ---- pairwise match + fused max over i and j ----
__global__ __launch_bounds__(256) void k_pairfused(const float* __restrict__ O,
        const float* __restrict__ NRM, const float* __restrict__ Wf,
        const float* __restrict__ Wb, float* __restrict__ V1, float* __restrict__ V2) {
  int b = blockIdx.x, lidx = blockIdx.y, d = blockIdx.z;
  int r1 = d;
  const float* A = O + ((size_t)r1 * M_ + b * S_) * 300;
  const float* Bm = O + ((size_t)3 * M_ + b * S_) * 300;
  const float* Wl = (d ? Wb : Wf) + (size_t)lidx * 300;
  __shared__ float As[64][33], Bs[64][33];
  int tid = threadIdx.x;
  int tx = tid & 15, ty = tid >> 4;
  int lr = tid >> 2, lc = (tid & 3) * 8;
  float acc[4][4] = {};
  for (int k0 = 0; k0 < 300; k0 += 32) {
    if (k0 + 32 <= 300) {
      float4 a0 = *(const float4*)(A + (size_t)lr * 300 + k0 + lc);
      float4 a1 = *(const float4*)(A + (size_t)lr * 300 + k0 + lc + 4);
      float4 w0 = *(const float4*)(Wl + k0 + lc);
      float4 w1 = *(const float4*)(Wl + k0 + lc + 4);
      As[lr][lc + 0] = a0.x * w0.x * w0.x; As[lr][lc + 1] = a0.y * w0.y * w0.y;
      As[lr][lc + 2] = a0.z * w0.z * w0.z; As[lr][lc + 3] = a0.w * w0.w * w0.w;
      As[lr][lc + 4] = a1.x * w1.x * w1.x; As[lr][lc + 5] = a1.y * w1.y * w1.y;
      As[lr][lc + 6] = a1.z * w1.z * w1.z; As[lr][lc + 7] = a1.w * w1.w * w1.w;
      float4 b0 = *(const float4*)(Bm + (size_t)lr * 300 + k0 + lc);
      float4 b1 = *(const float4*)(Bm + (size_t)lr * 300 + k0 + lc + 4);
      Bs[lr][lc + 0] = b0.x; Bs[lr][lc + 1] = b0.y; Bs[lr][lc + 2] = b0.z; Bs[lr][lc + 3] = b0.w;
      Bs[lr][lc + 4] = b1.x; Bs[lr][lc + 5] = b1.y; Bs[lr][lc + 6] = b1.z; Bs[lr][lc + 7] = b1.w;
    } else {
      #pragma unroll
      for (int q = 0; q < 8; ++q) {
        int k = k0 + lc + q;
        float w = (k < 300) ? Wl[k] : 0.f;
        As[lr][lc + q] = (k < 300) ? A[(size_t)lr * 300 + k] * w * w : 0.f;
        Bs[lr][lc + q] = (k < 300) ? Bm[(size_t)lr * 300 + k] : 0.f;
      }
    }
    __syncthreads();
    #pragma unroll
    for (int kk = 0; kk < 32; ++kk) {
      float av[4], bv[4];
      #pragma unroll
      for (int i = 0; i < 4; ++i) av[i] = As[ty * 4 + i][kk];
      #pragma unroll
      for (int j = 0; j < 4; ++j) bv[j] = Bs[tx * 4 + j][kk];
      #pragma unroll
      for (int i = 0; i < 4; ++i)
        #pragma unroll
        for (int j = 0; j < 4; ++j) acc[i][j] += av[i] * bv[j];
    }
    __syncthreads();
  }
  float n1[4], n2[4];
  #pragma unroll
  for (int i = 0; i < 4; ++i) {
    n1[i] = NRM[(size_t)r1 * M_ + b * S_ + ty * 4 + i];
    n2[i] = NRM[(size_t)3 * M_ + b * S_ + tx * 4 + i];
  }
  int offv = (d ? 100 : 20) + lidx;
  float mj[4], mi[4];
  #pragma unroll
  for (int q = 0; q < 4; ++q) { mj[q] = -INFINITY; mi[q] = -INFINITY; }
  #pragma unroll
  for (int i = 0; i < 4; ++i)
    #pragma unroll
    for (int j = 0; j < 4; ++j) {
      float v = acc[i][j] / (n1[i] * n2[j]);
      mj[i] = fmaxf(mj[i], v);
      mi[j] = fmaxf(mi[j], v);
    }
  #pragma unroll
  for (int off = 1; off < 16; off <<= 1)
    #pragma unroll
    for (int i = 0; i < 4; ++i) mj[i] = fmaxf(mj[i], __shfl_xor(mj[i], off));
  if (tx == 0)
    #pragma unroll
    for (int i = 0; i < 4; ++i)
      V1[((size_t)b * S_ + ty * 4 + i) * 160 + offv] = mj[i];
  float* red = &As[0][0];
  __syncthreads();
  #pragma unroll
  for (int j = 0; j < 4; ++j) red[(tx * 4 + j) * 16 + ty] = mi[j];
  __syncthreads();
  if (tid < 64) {
    float m = red[tid * 16];
    #pragma unroll
    for (int yy = 1; yy < 16; ++yy) m = fmaxf(m, red[tid * 16 + yy]);
    V2[((size_t)b * S_ + tid) * 160 + offv] = m;
  }
}

// ---------------- mean/max attention vectors MM[v][b][r][h] ----------------
__global__ __launch_bounds__(128) void k_meanmax(const float* __restrict__ O,
        const float* __restrict__ COS, const float* __restrict__ RS,
        const float* __restrict__ CS, float* __restrict__ MM) {
  int b = blockIdx.x, rg = blockIdx.y, v = blockIdx.z;
  int isMax = v >> 2, vv = v & 3;
  int d = vv & 1, s2side = vv >> 1;
  int srcrec = s2side ? 0 : 2;
  const float* SRC = O + ((size_t)srcrec * M_ + b * S_) * 300;
  const float* Cb = COS + ((size_t)d * 32 + b) * 4096;
  int tid = threadIdx.x;
  int h0 = tid, h1 = tid + 128, h2 = tid + 256;
  bool has2 = (h2 < 300);
  float init = isMax ? -INFINITY : 0.f;
  float acc[8][3];
  #pragma unroll
  for (int rr = 0; rr < 8; ++rr) { acc[rr][0] = init; acc[rr][1] = init; acc[rr][2] = init; }
  int r0 = rg * 8;
  for (int inner = 0; inner < 64; ++inner) {
    float s0 = SRC[(size_t)inner * 300 + h0];
    float s1 = SRC[(size_t)inner * 300 + h1];
    float s2v = has2 ? SRC[(size_t)inner * 300 + h2] : 0.f;
    #pragma unroll
    for (int rr = 0; rr < 8; ++rr) {
      int r = r0 + rr;
      float cv = s2side ? Cb[inner * 64 + r] : Cb[r * 64 + inner];
      if (isMax) {
        acc[rr][0] = fmaxf(acc[rr][0], cv * s0);
        acc[rr][1] = fmaxf(acc[rr][1], cv * s1);
        acc[rr][2] = fmaxf(acc[rr][2], cv * s2v);
      } else {
        acc[rr][0] += cv * s0; acc[rr][1] += cv * s1; acc[rr][2] += cv * s2v;
      }
    }
  }
  float* outp = MM + (size_t)v * 614400;
  for (int rr = 0; rr < 8; ++rr) {
    int r = r0 + rr;
    size_t o = ((size_t)b * S_ + r) * 300;
    if (isMax) {
      outp[o + h0] = acc[rr][0];
      outp[o + h1] = acc[rr][1];
      if (has2) outp[o + h2] = acc[rr][2];
    } else {
      float den = s2side ? CS[(d * 32 + b) * 64 + r] : RS[(d * 32 + b) * 64 + r];
      outp[o + h0] = acc[rr][0] / den;
      outp[o + h1] = acc[rr][1] / den;
      if (has2) outp[o + h2] = acc[rr][2] / den;
    }
  }
}

// ---------------- MFMA full-match (12 variants) ----------------
// sn/sa/sb[item][l] = P[item][h] . WSQ[l][h]; 32 items/block, 4 waves=(mt,nt).
__global__ __launch_bounds__(256) void k_fmm(const float* __restrict__ O,
        const float* __restrict__ MM, const f16* __restrict__ WSQ,
        float* __restrict__ V1, float* __restrict__ V2) {
  int ib = blockIdx.x, var = blockIdx.y;
  int tid = threadIdx.x;
  int w = tid >> 6, l = tid & 63, lo = l & 15, hi = l >> 4;
  int mt = w & 1, nt = w >> 1;
  __shared__ f16 Vs1[32][328];
  __shared__ f16 Vs2[32][328];
  __shared__ float zs[3][32][21];

  const float* s1f = O;
  const float* s1b = O + (size_t)M_ * 300;
  const float* s2f = O + (size_t)2 * M_ * 300;
  const float* s2b = O + (size_t)3 * M_ * 300;
  const float *v1b, *v2b;
  int v2fix = 0, v2off = 0, wi, co;
  float* outbase;
  switch (var) {
    case 0:  v1b = s1f; v2b = s2f; v2fix = 1; v2off = 63; wi = 0; outbase = V1; co = 0;   break;
    case 1:  v1b = s1f; v2b = MM + (size_t)0 * 614400; wi = 2; outbase = V1; co = 40; break;
    case 2:  v1b = s1f; v2b = MM + (size_t)4 * 614400; wi = 3; outbase = V1; co = 60; break;
    case 3:  v1b = s1b; v2b = s2b; v2fix = 1; v2off = 0; wi = 1; outbase = V1; co = 80; break;
    case 4:  v1b = s1b; v2b = MM + (size_t)1 * 614400; wi = 2; outbase = V1; co = 120; break;
    case 5:  v1b = s1b; v2b = MM + (size_t)5 * 614400; wi = 3; outbase = V1; co = 140; break;
    case 6:  v1b = s2f; v2b = s1f; v2fix = 1; v2off = 63; wi = 0; outbase = V2; co = 0; break;
    case 7:  v1b = s2f; v2b = MM + (size_t)2 * 614400; wi = 2; outbase = V2; co = 40; break;
    case 8:  v1b = s2f; v2b = MM + (size_t)6 * 614400; wi = 3; outbase = V2; co = 60; break;
    case 9:  v1b = s2b; v2b = s1b; v2fix = 1; v2off = 0; wi = 1; outbase = V2; co = 80; break;
    case 10: v1b = s2b; v2b = MM + (size_t)3 * 614400; wi = 2; outbase = V2; co = 120; break;
    default: v1b = s2b; v2b = MM + (size_t)7 * 614400; wi = 3; outbase = V2; co = 140; break;
  }
  // stage v1, v2 (32 rows x 320 padded) as f16
  int srow = tid >> 3, sseg = (tid & 7) * 40;
  int m1 = ib * 32 + srow;
  const float* r1 = v1b + (size_t)m1 * 300;
  int m2 = v2fix ? (m1 & ~63) + v2off : m1;
  const float* r2 = v2b + (size_t)m2 * 300;
  #pragma unroll
  for (int q = 0; q < 40; q += 4) {
    int k = sseg + q;
    if (k + 4 <= 300) {
      float4 x = *(const float4*)(r1 + k);
      float4 y = *(const float4*)(r2 + k);
      Vs1[srow][k + 0] = (f16)x.x; Vs1[srow][k + 1] = (f16)x.y;
      Vs1[srow][k + 2] = (f16)x.z; Vs1[srow][k + 3] = (f16)x.w;
      Vs2[srow][k + 0] = (f16)y.x; Vs2[srow][k + 1] = (f16)y.y;
      Vs2[srow][k + 2] = (f16)y.z; Vs2[srow][k + 3] = (f16)y.w;
    } else {
      #pragma unroll
      for (int j = 0; j < 4; ++j) {
        Vs1[srow][k + j] = (f16)((k + j < 300) ? r1[k + j] : 0.f);
        Vs2[srow][k + j] = (f16)((k + j < 300) ? r2[k + j] : 0.f);
      }
    }
  }
  __syncthreads();

  const f16* Wv = WSQ + (size_t)wi * 10240;
  f32x4 acc[3] = {};
  #pragma unroll
  for (int kt = 0; kt < 10; ++kt) {
    f16x8 a1 = *(const f16x8*)(&Vs1[mt * 16 + lo][kt * 32 + hi * 8]);
    f16x8 a2 = *(const f16x8*)(&Vs2[mt * 16 + lo][kt * 32 + hi * 8]);
    f16x8 bf = *(const f16x8*)(Wv + ((size_t)(nt * 16 + lo)) * 320 + kt * 32 + hi * 8);
    acc[0] = __builtin_amdgcn_mfma_f32_16x16x32_f16(a1 * a2, bf, acc[0], 0, 0, 0);
    acc[1] = __builtin_amdgcn_mfma_f32_16x16x32_f16(a1 * a1, bf, acc[1], 0, 0, 0);
    acc[2] = __builtin_amdgcn_mfma_f32_16x16x32_f16(a2 * a2, bf, acc[2], 0, 0, 0);
  }
  #pragma unroll
  for (int pt = 0; pt < 3; ++pt)
    #pragma unroll
    for (int r = 0; r < 4; ++r) {
      int item = mt * 16 + hi * 4 + r, lcol = nt * 16 + lo;
      if (lcol < 20) zs[pt][item][lcol] = acc[pt][r];
    }
  __syncthreads();
  for (int idx = tid; idx < 640; idx += 256) {
    int item = idx / 20, lcol = idx - item * 20;
    float sn = zs[0][item][lcol], sa = zs[1][item][lcol], sb = zs[2][item][lcol];
    float o = sn / (fmaxf(sqrtf(sa), EPSF) * fmaxf(sqrtf(sb), EPSF));
    outbase[(size_t)(ib * 32 + item) * 160 + co + lcol] = o;
  }
}

// ---------------- final MLP + log_softmax ----------------
__global__ __launch_bounds__(256) void k_mlp(const f16* __restrict__ H16,
        const float* __restrict__ W1T, const float* __restrict__ b1,
        const float* __restrict__ W2, const float* __restrict__ b2,
        float* __restrict__ out) {
  int b = blockIdx.x, tid = threadIdx.x;
  __shared__ float mvs[1200];
  __shared__ float xs[600];
  __shared__ float red[2][4];
  for (int i = tid; i < 1200; i += 256) {
    int r = i / 300, h = i - r * 300;
    mvs[i] = (float)H16[((size_t)r * 32 + b) * 320 + h];
  }
  __syncthreads();
  for (int o = tid; o < 600; o += 256) {
    float dot = b1[o];
    for (int k = 0; k < 1200; ++k) dot += mvs[k] * W1T[(size_t)k * 600 + o];
    xs[o] = tanhf(dot);
  }
  __syncthreads();
  float p0 = 0.f, p1 = 0.f;
  for (int k = tid; k < 600; k += 256) {
    float xv = xs[k];
    p0 += xv * W2[k];
    p1 += xv * W2[600 + k];
  }
  #pragma unroll
  for (int off = 32; off; off >>= 1) { p0 += __shfl_xor(p0, off); p1 += __shfl_xor(p1, off); }
  int w = tid >> 6;
  if ((tid & 63) == 0) { red[0][w] = p0; red[1][w] = p1; }
  __syncthreads();
  if (tid == 0) {
    float l0 = red[0][0] + red[0][1] + red[0][2] + red[0][3] + b2[0];
    float l1 = red[1][0] + red[1][1] + red[1][2] + red[1][3] + b2[1];
    float m = fmaxf(l0, l1);
    float lse = m + logf(expf(l0 - m) + expf(l1 - m));
    out[b * 2 + 0] = l0 - lse;
    out[b * 2 + 1] = l1 - lse;
  }
}

extern "C" void kernel_launch(void* const* d_in, const int* in_sizes, int n_in,
                              void* d_out, int out_size, void* d_ws, size_t ws_size,
                              hipStream_t stream) {
  (void)in_sizes; (void)out_size;
  if (n_in < 25) return;
  const float* emb    = (const float*)d_in[0];
  const float* cWihF  = (const float*)d_in[1];
  const float* cWhhF  = (const float*)d_in[2];
  const float* cbF    = (const float*)d_in[3];
  const float* cWihB  = (const float*)d_in[4];
  const float* cWhhB  = (const float*)d_in[5];
  const float* cbB    = (const float*)d_in[6];
  const float* aWihF  = (const float*)d_in[7];
  const float* aWhhF  = (const float*)d_in[8];
  const float* abF    = (const float*)d_in[9];
  const float* aWihB  = (const float*)d_in[10];
  const float* aWhhB  = (const float*)d_in[11];
  const float* abB    = (const float*)d_in[12];
  const float* WfullF = (const float*)d_in[13];
  const float* WfullB = (const float*)d_in[14];
  const float* WmaxpF = (const float*)d_in[15];
  const float* WmaxpB = (const float*)d_in[16];
  const float* WattnF = (const float*)d_in[17];
  const float* WmaxaF = (const float*)d_in[18];
  const float* pW1    = (const float*)d_in[19];
  const float* pb1    = (const float*)d_in[20];
  const float* pW2    = (const float*)d_in[21];
  const float* pb2    = (const float*)d_in[22];
  const int*   sa     = (const int*)d_in[23];
  const int*   sb     = (const int*)d_in[24];
  float* out = (float*)d_out;
  float* ws = (float*)d_ws;

  // ---- workspace layout (float offsets) ----
  if (ws_size < (size_t)10819712 * 4) return;
  float* W1T  = ws + 0;                        //  720000
  f16*   B16c = (f16*)(ws + 720000);           //  778240 f16 = 389120 fl
  f16*   B16a = (f16*)(ws + 1109120);          //  389120 f16 = 194560 fl
  f16*   Wh16 = (f16*)(ws + 1303680);          //  819200 fl
  f16*   WSQ  = (f16*)(ws + 2122880);          //   40960 f16 = 20480 fl
  unsigned int* Hbuf  = (unsigned int*)(ws + 2143360);  // 40960 u32
  unsigned int* flags = (unsigned int*)(ws + 2184320);  // 640 u32 (pad 1024)
  float* NRM  = ws + 2185344;                  //    8192
  float* COS  = ws + 2193536;                  //  262144
  float* RS   = ws + 2455680;                  //    4096
  float* CS   = ws + 2459776;                  //    4096
  float* V1   = ws + 2463872;                  //  327680
  float* V2   = ws + 2791552;                  //  327680
  f16*   XG2  = (f16*)(ws + 3119232);          // 10485760 f16 = 5242880 fl
  float* MM   = ws + 3119232;                  //  alias (4915200 <= 5242880)
  float* O    = ws + 8362112;                  //  2457600

  f16* WhCtx = Wh16;
  f16* WhAgg = Wh16 + (size_t)2 * 409600;

  // ---- weight prep ----
  k_transpose<<<dim3(38, 19), 256, 0, stream>>>(pW1, W1T, 600, 1200);
  k_wh16<<<1600, 256, 0, stream>>>(cWhhF, WhCtx);
  k_wh16<<<1600, 256, 0, stream>>>(cWhhB, WhCtx + 409600);
  k_wh16<<<1600, 256, 0, stream>>>(aWhhF, WhAgg);
  k_wh16<<<1600, 256, 0, stream>>>(aWhhB, WhAgg + 409600);
  k_wih16<<<3040, 256, 0, stream>>>(cWihF, cWihB, B16c, 300, 320);
  k_wih16<<<1520, 256, 0, stream>>>(aWihF, aWihB, B16a, 160, 160);
  k_wsq16<<<160, 256, 0, stream>>>(WfullF, WfullB, WattnF, WmaxaF, WSQ);

  // ---- context BiLSTM ----
  k_projm<<<dim3(16, 19), 256, 0, stream>>>(emb, sa, B16c, cbF, cbB, XG2, 0, 300, 320, 300);
  k_projm<<<dim3(16, 19), 256, 0, stream>>>(emb, sb, B16c, cbF, cbB, XG2, 2, 300, 320, 300);
  hipMemsetAsync(Hbuf, 0, 81920, stream);
  hipMemsetAsync(flags, 0, 4096, stream);
  k_lstm5<<<40, 512, 0, stream>>>(WhCtx, XG2, Hbuf, O, flags);

  // ---- matching ----
  k_norms<<<2048, 256, 0, stream>>>(O, NRM);
  k_cos<<<dim3(32, 2), 256, 0, stream>>>(O, NRM, COS);
  k_csum<<<dim3(32, 2), 64, 0, stream>>>(COS, RS, CS);
  k_pairfused<<<dim3(32, 20, 2), 256, 0, stream>>>(O, NRM, WmaxpF, WmaxpB, V1, V2);
  k_meanmax<<<dim3(32, 8, 8), 128, 0, stream>>>(O, COS, RS, CS, MM);
  k_fmm<<<dim3(64, 12), 256, 0, stream>>>(O, MM, WSQ, V1, V2);

  // ---- aggregation BiLSTM ----
  k_projm<<<dim3(16, 19), 256, 0, stream>>>(V1, nullptr, B16a, abF, abB, XG2, 0, 160, 160, 160);
  k_projm<<<dim3(16, 19), 256, 0, stream>>>(V2, nullptr, B16a, abF, abB, XG2, 2, 160, 160, 160);
  hipMemsetAsync(Hbuf, 0, 81920, stream);
  hipMemsetAsync(flags, 0, 4096, stream);
  k_lstm5<<<40, 512, 0, stream>>>(WhAgg, XG2, Hbuf, nullptr, flags);

  // ---- prediction head ----
  k_mlp<<<32, 256, 0, stream>>>((const f16*)Hbuf, W1T, pb1, pW2, pb2, out);
}

// Round 8
// 905.616 us; speedup vs baseline: 4.7507x; 1.0667x over previous
//
#include <hip/hip_runtime.h>
#include <math.h>

#define B_ 32
#define S_ 64
#define H_ 300
#define M_ 2048          // B*S
#define EPSF 1e-8f

typedef _Float16 f16;
typedef _Float16 f16x2 __attribute__((ext_vector_type(2)));
typedef _Float16 f16x4 __attribute__((ext_vector_type(4)));
typedef _Float16 f16x8 __attribute__((ext_vector_type(8)));
typedef float f32x4 __attribute__((ext_vector_type(4)));

// ---------------- transpose (R x C) -> (C x R) ----------------
__global__ __launch_bounds__(256) void k_transpose(const float* __restrict__ src,
        float* __restrict__ dst, int R, int C) {
  __shared__ float t[32][33];
  int tx = threadIdx.x & 31, ty = threadIdx.x >> 5;
  int c0 = blockIdx.x * 32, r0 = blockIdx.y * 32;
  #pragma unroll
  for (int q = 0; q < 4; ++q) {
    int r = r0 + ty + q * 8, c = c0 + tx;
    t[ty + q * 8][tx] = (r < R && c < C) ? src[(size_t)r * C + c] : 0.f;
  }
  __syncthreads();
  #pragma unroll
  for (int q = 0; q < 4; ++q) {
    int c = c0 + ty + q * 8, r = r0 + tx;
    if (c < C && r < R) dst[(size_t)c * R + r] = t[tx][ty + q * 8];
  }
}

// ---- Whh (1200x300 f32) -> f16 padded [4 g][320 u][320 k] ----
__global__ __launch_bounds__(256) void k_wh16(const float* __restrict__ W,
        f16* __restrict__ D) {
  int idx = blockIdx.x * 256 + threadIdx.x;
  if (idx >= 409600) return;
  int g = idx / 102400, rem = idx - g * 102400;
  int u = rem / 320, k = rem - u * 320;
  float v = (u < 300 && k < 300) ? W[((size_t)g * 300 + u) * 300 + k] : 0.f;
  D[idx] = (f16)v;
}

// ---- Wih F+B (each 1200 x Kreal) -> f16 [2432][Kpad], zero pad ----
__global__ __launch_bounds__(256) void k_wih16(const float* __restrict__ WF,
        const float* __restrict__ WB, f16* __restrict__ D, int Kreal, int Kpad) {
  int idx = blockIdx.x * 256 + threadIdx.x;
  if (idx >= 2432 * Kpad) return;
  int n = idx / Kpad, k = idx - n * Kpad;
  float v = 0.f;
  if (n < 2400 && k < Kreal) {
    int fb = n >= 1200;
    int nn = n - fb * 1200;
    v = (fb ? WB : WF)[(size_t)nn * Kreal + k];
  }
  D[idx] = (f16)v;
}

// ---- W^2: 6 x (20x300) -> f16 [6][32][320] ----
__global__ __launch_bounds__(256) void k_wsq16(const float* __restrict__ W0,
        const float* __restrict__ W1, const float* __restrict__ W2,
        const float* __restrict__ W3, const float* __restrict__ W4,
        const float* __restrict__ W5, f16* __restrict__ D) {
  int idx = blockIdx.x * 256 + threadIdx.x;
  if (idx >= 61440) return;
  int wi = idx / 10240, rem = idx - wi * 10240;
  int r = rem / 320, k = rem - r * 320;
  float v = 0.f;
  if (r < 20 && k < 300) {
    const float* W = wi == 0 ? W0 : wi == 1 ? W1 : wi == 2 ? W2
                   : wi == 3 ? W3 : wi == 4 ? W4 : W5;
    float w = W[(size_t)r * 300 + k];
    v = w * w;
  }
  D[idx] = (f16)v;
}

// ---------------- MFMA input projection, F+B fused, scatter to XG2 ----------
__global__ __launch_bounds__(256) void k_projm(const float* __restrict__ A,
        const int* __restrict__ gather, const f16* __restrict__ B16,
        const float* __restrict__ biasF, const float* __restrict__ biasB,
        f16* __restrict__ XG2, int recbase, int Kreal, int Kpad, int lda) {
  __shared__ f16 As[128][40];
  __shared__ f16 Bs[128][40];
  int tid = threadIdx.x;
  int m0 = blockIdx.x * 128, n0 = blockIdx.y * 128;
  int w = tid >> 6, l = tid & 63, lo = l & 15, hi = l >> 4;
  int srow = tid >> 1, sk = (tid & 1) * 16;
  int sA_s = (m0 + srow) >> 5, sA_b = (m0 + srow) & 31;
  int itemA = sA_b * 64 + sA_s;
  const float* Arow = gather ? (A + (size_t)gather[itemA] * lda)
                             : (A + (size_t)itemA * lda);
  const f16* Brow = B16 + (size_t)(n0 + srow) * Kpad;
  f32x4 acc[2][8] = {};
  int nkt = Kpad >> 5;
  for (int kt = 0; kt < nkt; ++kt) {
    int k0 = kt * 32;
    #pragma unroll
    for (int q = 0; q < 16; q += 4) {
      int k = k0 + sk + q;
      if (k + 4 <= Kreal) {
        float4 v = *(const float4*)(Arow + k);
        As[srow][sk + q + 0] = (f16)v.x; As[srow][sk + q + 1] = (f16)v.y;
        As[srow][sk + q + 2] = (f16)v.z; As[srow][sk + q + 3] = (f16)v.w;
      } else {
        #pragma unroll
        for (int j = 0; j < 4; ++j)
          As[srow][sk + q + j] = (f16)((k + j < Kreal) ? Arow[k + j] : 0.f);
      }
    }
    *(f16x8*)(&Bs[srow][sk]) = *(const f16x8*)(Brow + k0 + sk);
    *(f16x8*)(&Bs[srow][sk + 8]) = *(const f16x8*)(Brow + k0 + sk + 8);
    __syncthreads();
    f16x8 Bf[8];
    #pragma unroll
    for (int nt = 0; nt < 8; ++nt)
      Bf[nt] = *(const f16x8*)(&Bs[nt * 16 + lo][hi * 8]);
    #pragma unroll
    for (int mt = 0; mt < 2; ++mt) {
      f16x8 Af = *(const f16x8*)(&As[w * 32 + mt * 16 + lo][hi * 8]);
      #pragma unroll
      for (int nt = 0; nt < 8; ++nt)
        acc[mt][nt] = __builtin_amdgcn_mfma_f32_16x16x32_f16(Af, Bf[nt], acc[mt][nt], 0, 0, 0);
    }
    __syncthreads();
  }
  int s = (m0 >> 5) + w;
  #pragma unroll
  for (int nt = 0; nt < 8; ++nt) {
    int n = n0 + nt * 16 + lo;
    if (n >= 2400) continue;
    int fb = n >= 1200;
    int nn = n - fb * 1200;
    int g = nn / 300;
    int u = nn - g * 300;
    int jb = u >> 5, ul = u & 31, nh = ul >> 4, lo2 = ul & 15;
    int rec = recbase + fb;
    int t = fb ? 63 - s : s;
    float bias = fb ? biasB[nn] : biasF[nn];
    size_t tbase = ((((size_t)(rec * 64 + t) * 10 + jb) * 4 + g) * 2 + nh) * 512
                   + (size_t)(hi * 16 + lo2) * 4;
    #pragma unroll
    for (int mt = 0; mt < 2; ++mt) {
      f16x4 hv;
      #pragma unroll
      for (int r = 0; r < 4; ++r) hv[r] = (f16)(acc[mt][nt][r] + bias);
      *(f16x4*)(XG2 + tbase + mt * 256) = hv;
    }
  }
}

// ---------------- distributed MFMA LSTM, per-producer flag sync ----------
// O stores moved AFTER the flag release (off the serial chain); also emits
// f16 copy O16 [rec][b*64+t][320] for downstream MFMA consumers.
__global__ __launch_bounds__(512, 1) void k_lstm5(
    const f16* __restrict__ Wh, const f16* __restrict__ XG2,
    unsigned int* __restrict__ Hbuf, float* __restrict__ O,
    unsigned int* __restrict__ O16u, unsigned int* __restrict__ flags) {
  int bid = blockIdx.x;
  int rec = bid / 10, jb = bid - rec * 10;
  int tid = threadIdx.x;
  int w = tid >> 6, l = tid & 63, lo = l & 15, hi = l >> 4;
  int g = w & 3, nh = w >> 2;

  __shared__ f16 Hs[32][328];
  __shared__ float zs[4][32][33];

  const f16* Wd = Wh + (size_t)(rec & 1) * 409600;
  int u_t = jb * 32 + nh * 16 + lo;
  f16x8 Bf[10];
  #pragma unroll
  for (int kt = 0; kt < 10; ++kt)
    Bf[kt] = *(const f16x8*)(Wd + ((size_t)g * 320 + u_t) * 320 + kt * 32 + hi * 8);

  int cb = tid >> 4, cup = tid & 15;
  int u0c = jb * 32 + cup * 2;
  float c0 = 0.f, c1 = 0.f;
  unsigned int* fl = flags + rec * 160;
  const f16* xgbase = XG2 + ((size_t)(rec * 64) * 10 + jb) * 4096
                      + ((size_t)(g * 2 + nh)) * 512 + l * 4;

  for (int t = 0; t < 64; ++t) {
    const f16* xt = xgbase + (size_t)t * 40960;
    f16x4 xv[2];
    #pragma unroll
    for (int mt = 0; mt < 2; ++mt) xv[mt] = *(const f16x4*)(xt + mt * 256);

    if (t > 0) {
      if (tid < 10) {
        while (__hip_atomic_load(fl + tid * 16, __ATOMIC_RELAXED,
                                 __HIP_MEMORY_SCOPE_AGENT) < (unsigned)t)
          __builtin_amdgcn_s_sleep(1);
      }
      __syncthreads();
    }
    {
      unsigned long long* Hg = (unsigned long long*)
          (Hbuf + ((size_t)(t & 1) * 4 + rec) * 5120);
      #pragma unroll
      for (int q = 0; q < 5; ++q) {
        int idx = q * 512 + tid;
        unsigned long long v = __hip_atomic_load(Hg + idx, __ATOMIC_RELAXED,
                                                 __HIP_MEMORY_SCOPE_AGENT);
        int b = idx / 80, rm = idx - b * 80;
        *(unsigned long long*)(&Hs[b][rm * 4]) = v;
      }
    }
    __syncthreads();

    f32x4 acc[2] = {};
    #pragma unroll
    for (int kt = 0; kt < 10; ++kt) {
      #pragma unroll
      for (int mt = 0; mt < 2; ++mt) {
        f16x8 Af = *(const f16x8*)(&Hs[mt * 16 + lo][kt * 32 + hi * 8]);
        acc[mt] = __builtin_amdgcn_mfma_f32_16x16x32_f16(Af, Bf[kt], acc[mt], 0, 0, 0);
      }
    }
    #pragma unroll
    for (int mt = 0; mt < 2; ++mt)
      #pragma unroll
      for (int r = 0; r < 4; ++r)
        zs[g][mt * 16 + hi * 4 + r][nh * 16 + lo] = acc[mt][r] + (float)xv[mt][r];
    __syncthreads();

    int tt = (rec & 1) ? 63 - t : t;
    float h0n, h1n;
    {
      int uu = cup * 2;
      float zi = zs[0][cb][uu], zf = zs[1][cb][uu];
      float zg = zs[2][cb][uu], zo = zs[3][cb][uu];
      float si = 1.f / (1.f + expf(-zi));
      float sf = 1.f / (1.f + expf(-zf));
      float so = 1.f / (1.f + expf(-zo));
      float cn = sf * c0 + si * tanhf(zg);
      h0n = so * tanhf(cn);
      c0 = cn;
      zi = zs[0][cb][uu + 1]; zf = zs[1][cb][uu + 1];
      zg = zs[2][cb][uu + 1]; zo = zs[3][cb][uu + 1];
      si = 1.f / (1.f + expf(-zi));
      sf = 1.f / (1.f + expf(-zf));
      so = 1.f / (1.f + expf(-zo));
      cn = sf * c1 + si * tanhf(zg);
      h1n = so * tanhf(cn);
      c1 = cn;
    }
    if (u0c >= 300) { h0n = 0.f; h1n = 0.f; }
    union { f16x2 h; unsigned int u; } pk;
    pk.h[0] = (f16)h0n; pk.h[1] = (f16)h1n;
    unsigned int* Hw = Hbuf + ((size_t)((t + 1) & 1) * 4 + rec) * 5120;
    __hip_atomic_store(Hw + cb * 160 + jb * 16 + cup, pk.u, __ATOMIC_RELAXED,
                       __HIP_MEMORY_SCOPE_AGENT);
    asm volatile("s_waitcnt vmcnt(0)" ::: "memory");   // h stores acked at L3
    __syncthreads();
    if (tid == 0)
      __hip_atomic_store(fl + jb * 16, (unsigned)(t + 1), __ATOMIC_RELAXED,
                         __HIP_MEMORY_SCOPE_AGENT);
    // O stores AFTER the release — retire in the shadow of the next step
    if (O) {
      O16u[((size_t)rec * 2048 + cb * 64 + tt) * 160 + jb * 16 + cup] = pk.u;
      if (u0c < 300) {
        float2 ov; ov.x = h0n; ov.y = h1n;
        *(float2*)(O + ((size_t)rec * 2048 + cb * 64 + tt) * 300 + u0c) = ov;
      }
    }
  }
}

// ---------------- MFMA cosine matrices + fused row/col sums ----------------
__global__ __launch_bounds__(256) void k_cos2(const f16* __restrict__ O16,
        float* __restrict__ COS, float* __restrict__ RS, float* __restrict__ CS) {
  int b = blockIdx.x, d = blockIdx.y;
  int r1 = d, r2 = 2 + d;
  __shared__ f16 As[64][328];
  __shared__ f16 Bs[64][328];
  __shared__ float ninv[2][64];
  __shared__ float ctile[64][68];
  int tid = threadIdx.x;
  int w = tid >> 6, l = tid & 63, lo = l & 15, hi = l >> 4;
  int srow = tid >> 2, sseg = (tid & 3) * 80;
  const f16* ap = O16 + ((size_t)r1 * 2048 + b * 64 + srow) * 320 + sseg;
  const f16* bp = O16 + ((size_t)r2 * 2048 + b * 64 + srow) * 320 + sseg;
  #pragma unroll
  for (int q = 0; q < 80; q += 8) {
    *(f16x8*)(&As[srow][sseg + q]) = *(const f16x8*)(ap + q);
    *(f16x8*)(&Bs[srow][sseg + q]) = *(const f16x8*)(bp + q);
  }
  __syncthreads();
  if (tid < 128) {
    int which = tid >> 6, row = tid & 63;
    float s = 0.f;
    for (int k = 0; k < 320; ++k) {
      float v = which ? (float)Bs[row][k] : (float)As[row][k];
      s += v * v;
    }
    ninv[which][row] = 1.f / sqrtf(s);
  }
  f32x4 acc[4] = {};
  #pragma unroll
  for (int kt = 0; kt < 10; ++kt) {
    f16x8 Af = *(const f16x8*)(&As[w * 16 + lo][kt * 32 + hi * 8]);
    #pragma unroll
    for (int jt = 0; jt < 4; ++jt) {
      f16x8 Bf = *(const f16x8*)(&Bs[jt * 16 + lo][kt * 32 + hi * 8]);
      acc[jt] = __builtin_amdgcn_mfma_f32_16x16x32_f16(Af, Bf, acc[jt], 0, 0, 0);
    }
  }
  __syncthreads();      // ninv ready
  float n1i[4];
  #pragma unroll
  for (int r = 0; r < 4; ++r) n1i[r] = ninv[0][w * 16 + hi * 4 + r];
  float* outp = COS + ((size_t)d * 32 + b) * 4096;
  #pragma unroll
  for (int jt = 0; jt < 4; ++jt) {
    float n2j = ninv[1][jt * 16 + lo];
    #pragma unroll
    for (int r = 0; r < 4; ++r) {
      int i = w * 16 + hi * 4 + r, j = jt * 16 + lo;
      float v = acc[jt][r] * n1i[r] * n2j;
      ctile[i][j] = v;
      outp[i * 64 + j] = v;
    }
  }
  __syncthreads();
  if (tid < 64) {
    float rs = 0.f;
    for (int k = 0; k < 64; ++k) rs += ctile[tid][k];
    RS[(d * 32 + b) * 64 + tid] = rs;
  } else if (tid < 128) {
    int j = tid - 64;
    float cs = 0.f;
    for (int k = 0; k < 64; ++k) cs += ctile[k][j];
    CS[(d * 32 + b) * 64 + j] = cs;
  }
}

// ---------------- MFMA pairwise match + fused max over i and j ------------
// block (b,d): A(l) = s1 ⊙ W²_l in-register; C = A·s2b^T; norms in-block.
__global__ __launch_bounds__(256) void k_pairf2(const f16* __restrict__ O16,
        const f16* __restrict__ WSQ, float* __restrict__ V1, float* __restrict__ V2) {
  int b = blockIdx.x, d = blockIdx.y;
  __shared__ f16 As[64][328];
  __shared__ f16 Bs[64][328];
  __shared__ float ninv[2][64];
  __shared__ float mjb[64][20];
  __shared__ float mir[4][64][20];
  int tid = threadIdx.x;
  int w = tid >> 6, l = tid & 63, lo = l & 15, hi = l >> 4;
  int srow = tid >> 2, sseg = (tid & 3) * 80;
  const f16* ap = O16 + ((size_t)d * 2048 + b * 64 + srow) * 320 + sseg;       // s1f/s1b
  const f16* bp = O16 + ((size_t)3 * 2048 + b * 64 + srow) * 320 + sseg;       // s2b
  #pragma unroll
  for (int q = 0; q < 80; q += 8) {
    *(f16x8*)(&As[srow][sseg + q]) = *(const f16x8*)(ap + q);
    *(f16x8*)(&Bs[srow][sseg + q]) = *(const f16x8*)(bp + q);
  }
  __syncthreads();
  if (tid < 128) {
    int which = tid >> 6, row = tid & 63;
    float s = 0.f;
    for (int k = 0; k < 320; ++k) {
      float v = which ? (float)Bs[row][k] : (float)As[row][k];
      s += v * v;
    }
    ninv[which][row] = 1.f / sqrtf(s);
  }
  __syncthreads();
  float n1i[4], n2i[4];
  #pragma unroll
  for (int r = 0; r < 4; ++r) n1i[r] = ninv[0][w * 16 + hi * 4 + r];
  #pragma unroll
  for (int jt = 0; jt < 4; ++jt) n2i[jt] = ninv[1][jt * 16 + lo];

  const f16* Wv = WSQ + (size_t)(4 + d) * 10240;
  for (int lq = 0; lq < 20; ++lq) {
    f32x4 acc[4] = {};
    #pragma unroll
    for (int kt = 0; kt < 10; ++kt) {
      f16x8 a = *(const f16x8*)(&As[w * 16 + lo][kt * 32 + hi * 8]);
      f16x8 wf = *(const f16x8*)(Wv + (size_t)lq * 320 + kt * 32 + hi * 8);
      f16x8 aw = a * wf;
      #pragma unroll
      for (int jt = 0; jt < 4; ++jt) {
        f16x8 bf = *(const f16x8*)(&Bs[jt * 16 + lo][kt * 32 + hi * 8]);
        acc[jt] = __builtin_amdgcn_mfma_f32_16x16x32_f16(aw, bf, acc[jt], 0, 0, 0);
      }
    }
    // mj[i]: max over j (scale by n2 per-jt first, n1 after)
    float mjr[4];
    #pragma unroll
    for (int r = 0; r < 4; ++r) {
      float m = acc[0][r] * n2i[0];
      #pragma unroll
      for (int jt = 1; jt < 4; ++jt) m = fmaxf(m, acc[jt][r] * n2i[jt]);
      mjr[r] = m;
    }
    #pragma unroll
    for (int off = 1; off < 16; off <<= 1)
      #pragma unroll
      for (int r = 0; r < 4; ++r) mjr[r] = fmaxf(mjr[r], __shfl_xor(mjr[r], off));
    if (lo == 0)
      #pragma unroll
      for (int r = 0; r < 4; ++r)
        mjb[w * 16 + hi * 4 + r][lq] = mjr[r] * n1i[r];
    // mi[j]: max over i (scale by n1 per-r first, n2 after)
    float milo[4];
    #pragma unroll
    for (int jt = 0; jt < 4; ++jt) {
      float m = acc[jt][0] * n1i[0];
      #pragma unroll
      for (int r = 1; r < 4; ++r) m = fmaxf(m, acc[jt][r] * n1i[r]);
      milo[jt] = m;
    }
    #pragma unroll
    for (int r = 0; r < 4; ++r) {
      #pragma unroll
      for (int jt = 0; jt < 4; ++jt) {
        float o16 = __shfl_xor(milo[jt], 16);
        float o32 = __shfl_xor(fmaxf(milo[jt], o16), 32);
        (void)r;
        milo[jt] = fmaxf(fmaxf(milo[jt], o16), o32);
      }
      break;
    }
    if (hi == 0)
      #pragma unroll
      for (int jt = 0; jt < 4; ++jt)
        mir[w][jt * 16 + lo][lq] = milo[jt] * n2i[jt];
  }
  __syncthreads();
  int offv0 = (d ? 100 : 20);
  for (int idx = tid; idx < 1280; idx += 256) {
    int i = idx / 20, lq = idx - i * 20;
    V1[((size_t)b * 64 + i) * 160 + offv0 + lq] = mjb[i][lq];
    float m = fmaxf(fmaxf(mir[0][i][lq], mir[1][i][lq]),
                    fmaxf(mir[2][i][lq], mir[3][i][lq]));
    V2[((size_t)b * 64 + i) * 160 + offv0 + lq] = m;
  }
}

// ---------------- mean/max attention vectors MM[v][b][r][h] ----------------
__global__ __launch_bounds__(128) void k_meanmax(const float* __restrict__ O,
        const float* __restrict__ COS, const float* __restrict__ RS,
        const float* __restrict__ CS, float* __restrict__ MM) {
  int b = blockIdx.x, rg = blockIdx.y, v = blockIdx.z;
  int isMax = v >> 2, vv = v & 3;
  int d = vv & 1, s2side = vv >> 1;
  int srcrec = s2side ? 0 : 2;
  const float* SRC = O + ((size_t)srcrec * M_ + b * S_) * 300;
  const float* Cb = COS + ((size_t)d * 32 + b) * 4096;
  int tid = threadIdx.x;
  int h0 = tid, h1 = tid + 128, h2 = tid + 256;
  bool has2 = (h2 < 300);
  float init = isMax ? -INFINITY : 0.f;
  float acc[8][3];
  #pragma unroll
  for (int rr = 0; rr < 8; ++rr) { acc[rr][0] = init; acc[rr][1] = init; acc[rr][2] = init; }
  int r0 = rg * 8;
  for (int inner = 0; inner < 64; ++inner) {
    float s0 = SRC[(size_t)inner * 300 + h0];
    float s1 = SRC[(size_t)inner * 300 + h1];
    float s2v = has2 ? SRC[(size_t)inner * 300 + h2] : 0.f;
    #pragma unroll
    for (int rr = 0; rr < 8; ++rr) {
      int r = r0 + rr;
      float cv = s2side ? Cb[inner * 64 + r] : Cb[r * 64 + inner];
      if (isMax) {
        acc[rr][0] = fmaxf(acc[rr][0], cv * s0);
        acc[rr][1] = fmaxf(acc[rr][1], cv * s1);
        acc[rr][2] = fmaxf(acc[rr][2], cv * s2v);
      } else {
        acc[rr][0] += cv * s0; acc[rr][1] += cv * s1; acc[rr][2] += cv * s2v;
      }
    }
  }
  float* outp = MM + (size_t)v * 614400;
  for (int rr = 0; rr < 8; ++rr) {
    int r = r0 + rr;
    size_t o = ((size_t)b * S_ + r) * 300;
    if (isMax) {
      outp[o + h0] = acc[rr][0];
      outp[o + h1] = acc[rr][1];
      if (has2) outp[o + h2] = acc[rr][2];
    } else {
      float den = s2side ? CS[(d * 32 + b) * 64 + r] : RS[(d * 32 + b) * 64 + r];
      outp[o + h0] = acc[rr][0] / den;
      outp[o + h1] = acc[rr][1] / den;
      if (has2) outp[o + h2] = acc[rr][2] / den;
    }
  }
}

// ---------------- MFMA full-match (12 variants) ----------------
__global__ __launch_bounds__(256) void k_fmm(const float* __restrict__ O,
        const float* __restrict__ MM, const f16* __restrict__ WSQ,
        float* __restrict__ V1, float* __restrict__ V2) {
  int ib = blockIdx.x, var = blockIdx.y;
  int tid = threadIdx.x;
  int w = tid >> 6, l = tid & 63, lo = l & 15, hi = l >> 4;
  int mt = w & 1, nt = w >> 1;
  __shared__ f16 Vs1[32][328];
  __shared__ f16 Vs2[32][328];
  __shared__ float zs[3][32][21];

  const float* s1f = O;
  const float* s1b = O + (size_t)M_ * 300;
  const float* s2f = O + (size_t)2 * M_ * 300;
  const float* s2b = O + (size_t)3 * M_ * 300;
  const float *v1b, *v2b;
  int v2fix = 0, v2off = 0, wi, co;
  float* outbase;
  switch (var) {
    case 0:  v1b = s1f; v2b = s2f; v2fix = 1; v2off = 63; wi = 0; outbase = V1; co = 0;   break;
    case 1:  v1b = s1f; v2b = MM + (size_t)0 * 614400; wi = 2; outbase = V1; co = 40; break;
    case 2:  v1b = s1f; v2b = MM + (size_t)4 * 614400; wi = 3; outbase = V1; co = 60; break;
    case 3:  v1b = s1b; v2b = s2b; v2fix = 1; v2off = 0; wi = 1; outbase = V1; co = 80; break;
    case 4:  v1b = s1b; v2b = MM + (size_t)1 * 614400; wi = 2; outbase = V1; co = 120; break;
    case 5:  v1b = s1b; v2b = MM + (size_t)5 * 614400; wi = 3; outbase = V1; co = 140; break;
    case 6:  v1b = s2f; v2b = s1f; v2fix = 1; v2off = 63; wi = 0; outbase = V2; co = 0; break;
    case 7:  v1b = s2f; v2b = MM + (size_t)2 * 614400; wi = 2; outbase = V2; co = 40; break;
    case 8:  v1b = s2f; v2b = MM + (size_t)6 * 614400; wi = 3; outbase = V2; co = 60; break;
    case 9:  v1b = s2b; v2b = s1b; v2fix = 1; v2off = 0; wi = 1; outbase = V2; co = 80; break;
    case 10: v1b = s2b; v2b = MM + (size_t)3 * 614400; wi = 2; outbase = V2; co = 120; break;
    default: v1b = s2b; v2b = MM + (size_t)7 * 614400; wi = 3; outbase = V2; co = 140; break;
  }
  int srow = tid >> 3, sseg = (tid & 7) * 40;
  int m1 = ib * 32 + srow;
  const float* r1 = v1b + (size_t)m1 * 300;
  int m2 = v2fix ? (m1 & ~63) + v2off : m1;
  const float* r2 = v2b + (size_t)m2 * 300;
  #pragma unroll
  for (int q = 0; q < 40; q += 4) {
    int k = sseg + q;
    if (k + 4 <= 300) {
      float4 x = *(const float4*)(r1 + k);
      float4 y = *(const float4*)(r2 + k);
      Vs1[srow][k + 0] = (f16)x.x; Vs1[srow][k + 1] = (f16)x.y;
      Vs1[srow][k + 2] = (f16)x.z; Vs1[srow][k + 3] = (f16)x.w;
      Vs2[srow][k + 0] = (f16)y.x; Vs2[srow][k + 1] = (f16)y.y;
      Vs2[srow][k + 2] = (f16)y.z; Vs2[srow][k + 3] = (f16)y.w;
    } else {
      #pragma unroll
      for (int j = 0; j < 4; ++j) {
        Vs1[srow][k + j] = (f16)((k + j < 300) ? r1[k + j] : 0.f);
        Vs2[srow][k + j] = (f16)((k + j < 300) ? r2[k + j] : 0.f);
      }
    }
  }
  __syncthreads();

  const f16* Wv = WSQ + (size_t)wi * 10240;
  f32x4 acc[3] = {};
  #pragma unroll
  for (int kt = 0; kt < 10; ++kt) {
    f16x8 a1 = *(const f16x8*)(&Vs1[mt * 16 + lo][kt * 32 + hi * 8]);
    f16x8 a2 = *(const f16x8*)(&Vs2[mt * 16 + lo][kt * 32 + hi * 8]);
    f16x8 bf = *(const f16x8*)(Wv + ((size_t)(nt * 16 + lo)) * 320 + kt * 32 + hi * 8);
    acc[0] = __builtin_amdgcn_mfma_f32_16x16x32_f16(a1 * a2, bf, acc[0], 0, 0, 0);
    acc[1] = __builtin_amdgcn_mfma_f32_16x16x32_f16(a1 * a1, bf, acc[1], 0, 0, 0);
    acc[2] = __builtin_amdgcn_mfma_f32_16x16x32_f16(a2 * a2, bf, acc[2], 0, 0, 0);
  }
  #pragma unroll
  for (int pt = 0; pt < 3; ++pt)
    #pragma unroll
    for (int r = 0; r < 4; ++r) {
      int item = mt * 16 + hi * 4 + r, lcol = nt * 16 + lo;
      if (lcol < 20) zs[pt][item][lcol] = acc[pt][r];
    }
  __syncthreads();
  for (int idx = tid; idx < 640; idx += 256) {
    int item = idx / 20, lcol = idx - item * 20;
    float sn = zs[0][item][lcol], sa = zs[1][item][lcol], sb = zs[2][item][lcol];
    float o = sn / (fmaxf(sqrtf(sa), EPSF) * fmaxf(sqrtf(sb), EPSF));
    outbase[(size_t)(ib * 32 + item) * 160 + co + lcol] = o;
  }
}

// ---------------- final MLP + log_softmax ----------------
__global__ __launch_bounds__(256) void k_mlp(const f16* __restrict__ H16,
        const float* __restrict__ W1T, const float* __restrict__ b1,
        const float* __restrict__ W2, const float* __restrict__ b2,
        float* __restrict__ out) {
  int b = blockIdx.x, tid = threadIdx.x;
  __shared__ float mvs[1200];
  __shared__ float xs[600];
  __shared__ float red[2][4];
  for (int i = tid; i < 1200; i += 256) {
    int r = i / 300, h = i - r * 300;
    mvs[i] = (float)H16[((size_t)r * 32 + b) * 320 + h];
  }
  __syncthreads();
  for (int o = tid; o < 600; o += 256) {
    float dot = b1[o];
    for (int k = 0; k < 1200; ++k) dot += mvs[k] * W1T[(size_t)k * 600 + o];
    xs[o] = tanhf(dot);
  }
  __syncthreads();
  float p0 = 0.f, p1 = 0.f;
  for (int k = tid; k < 600; k += 256) {
    float xv = xs[k];
    p0 += xv * W2[k];
    p1 += xv * W2[600 + k];
  }
  #pragma unroll
  for (int off = 32; off; off >>= 1) { p0 += __shfl_xor(p0, off); p1 += __shfl_xor(p1, off); }
  int w = tid >> 6;
  if ((tid & 63) == 0) { red[0][w] = p0; red[1][w] = p1; }
  __syncthreads();
  if (tid == 0) {
    float l0 = red[0][0] + red[0][1] + red[0][2] + red[0][3] + b2[0];
    float l1 = red[1][0] + red[1][1] + red[1][2] + red[1][3] + b2[1];
    float m = fmaxf(l0, l1);
    float lse = m + logf(expf(l0 - m) + expf(l1 - m));
    out[b * 2 + 0] = l0 - lse;
    out[b * 2 + 1] = l1 - lse;
  }
}

extern "C" void kernel_launch(void* const* d_in, const int* in_sizes, int n_in,
                              void* d_out, int out_size, void* d_ws, size_t ws_size,
                              hipStream_t stream) {
  (void)in_sizes; (void)out_size;
  if (n_in < 25) return;
  const float* emb    = (const float*)d_in[0];
  const float* cWihF  = (const float*)d_in[1];
  const float* cWhhF  = (const float*)d_in[2];
  const float* cbF    = (const float*)d_in[3];
  const float* cWihB  = (const float*)d_in[4];
  const float* cWhhB  = (const float*)d_in[5];
  const float* cbB    = (const float*)d_in[6];
  const float* aWihF  = (const float*)d_in[7];
  const float* aWhhF  = (const float*)d_in[8];
  const float* abF    = (const float*)d_in[9];
  const float* aWihB  = (const float*)d_in[10];
  const float* aWhhB  = (const float*)d_in[11];
  const float* abB    = (const float*)d_in[12];
  const float* WfullF = (const float*)d_in[13];
  const float* WfullB = (const float*)d_in[14];
  const float* WmaxpF = (const float*)d_in[15];
  const float* WmaxpB = (const float*)d_in[16];
  const float* WattnF = (const float*)d_in[17];
  const float* WmaxaF = (const float*)d_in[18];
  const float* pW1    = (const float*)d_in[19];
  const float* pb1    = (const float*)d_in[20];
  const float* pW2    = (const float*)d_in[21];
  const float* pb2    = (const float*)d_in[22];
  const int*   sa     = (const int*)d_in[23];
  const int*   sb     = (const int*)d_in[24];
  float* out = (float*)d_out;
  float* ws = (float*)d_ws;

  // ---- workspace layout (float offsets) ----
  if (ws_size < (size_t)12132480 * 4) return;
  float* W1T  = ws + 0;                        //  720000
  f16*   B16c = (f16*)(ws + 720000);           //  389120 fl
  f16*   B16a = (f16*)(ws + 1109120);          //  194560 fl
  f16*   Wh16 = (f16*)(ws + 1303680);          //  819200 fl
  f16*   WSQ  = (f16*)(ws + 2122880);          //   30720 fl (6 x 32 x 320 f16)
  unsigned int* Hbuf  = (unsigned int*)(ws + 2153600);  // 40960 u32
  unsigned int* flags = (unsigned int*)(ws + 2194560);  // 1024 fl
  float* COS  = ws + 2195584;                  //  262144
  float* RS   = ws + 2457728;                  //    4096
  float* CS   = ws + 2461824;                  //    4096
  float* V1   = ws + 2465920;                  //  327680
  float* V2   = ws + 2793600;                  //  327680
  unsigned int* O16u = (unsigned int*)(ws + 3121280);   // 1310720 fl (f16 copy)
  f16*   O16  = (f16*)O16u;
  f16*   XG2  = (f16*)(ws + 4432000);          // 5242880 fl
  float* MM   = ws + 4432000;                  //  alias (4915200 <= 5242880)
  float* O    = ws + 9674880;                  //  2457600

  f16* WhCtx = Wh16;
  f16* WhAgg = Wh16 + (size_t)2 * 409600;

  // ---- weight prep ----
  k_transpose<<<dim3(38, 19), 256, 0, stream>>>(pW1, W1T, 600, 1200);
  k_wh16<<<1600, 256, 0, stream>>>(cWhhF, WhCtx);
  k_wh16<<<1600, 256, 0, stream>>>(cWhhB, WhCtx + 409600);
  k_wh16<<<1600, 256, 0, stream>>>(aWhhF, WhAgg);
  k_wh16<<<1600, 256, 0, stream>>>(aWhhB, WhAgg + 409600);
  k_wih16<<<3040, 256, 0, stream>>>(cWihF, cWihB, B16c, 300, 320);
  k_wih16<<<1520, 256, 0, stream>>>(aWihF, aWihB, B16a, 160, 160);
  k_wsq16<<<240, 256, 0, stream>>>(WfullF, WfullB, WattnF, WmaxaF, WmaxpF, WmaxpB, WSQ);

  // ---- context BiLSTM ----
  k_projm<<<dim3(16, 19), 256, 0, stream>>>(emb, sa, B16c, cbF, cbB, XG2, 0, 300, 320, 300);
  k_projm<<<dim3(16, 19), 256, 0, stream>>>(emb, sb, B16c, cbF, cbB, XG2, 2, 300, 320, 300);
  hipMemsetAsync(Hbuf, 0, 81920, stream);
  hipMemsetAsync(flags, 0, 4096, stream);
  k_lstm5<<<40, 512, 0, stream>>>(WhCtx, XG2, Hbuf, O, O16u, flags);

  // ---- matching ----
  k_cos2<<<dim3(32, 2), 256, 0, stream>>>(O16, COS, RS, CS);
  k_pairf2<<<dim3(32, 2), 256, 0, stream>>>(O16, WSQ, V1, V2);
  k_meanmax<<<dim3(32, 8, 8), 128, 0, stream>>>(O, COS, RS, CS, MM);
  k_fmm<<<dim3(64, 12), 256, 0, stream>>>(O, MM, WSQ, V1, V2);

  // ---- aggregation BiLSTM ----
  k_projm<<<dim3(16, 19), 256, 0, stream>>>(V1, nullptr, B16a, abF, abB, XG2, 0, 160, 160, 160);
  k_projm<<<dim3(16, 19), 256, 0, stream>>>(V2, nullptr, B16a, abF, abB, XG2, 2, 160, 160, 160);
  hipMemsetAsync(Hbuf, 0, 81920, stream);
  hipMemsetAsync(flags, 0, 4096, stream);
  k_lstm5<<<40, 512, 0, stream>>>(WhAgg, XG2, Hbuf, nullptr, nullptr, flags);

  // ---- prediction head ----
  k_mlp<<<32, 256, 0, stream>>>((const f16*)Hbuf, W1T, pb1, pW2, pb2, out);
}